// Round 1
// baseline (326.163 us; speedup 1.0000x reference)
//
#include <hip/hip_runtime.h>
#include <math.h>

#define DEV static __device__ __forceinline__

constexpr float MIN_NORM = 1e-15f;
constexpr float BALL_EPS = 1e-5f;
constexpr int D = 512;          // feature dim (fixed by problem)
constexpr int BM = 64, BN = 64, BK = 16;

DEV float wave_sum(float v) {
#pragma unroll
    for (int o = 32; o > 0; o >>= 1) v += __shfl_xor(v, o, 64);
    return v;
}

DEV float tanh_clip(float x) {
    x = fminf(fmaxf(x, -15.0f), 15.0f);
    return tanhf(x);
}

// ---------------------------------------------------------------------------
// Kernel A: per-row preprocessing. One wave (64 lanes) per row, 8 elems/lane.
// Computes res = project(mobius_add(expmap0(att_q,c), expmap0(rel,c), c), c)
// plus per-row scalars x2 = ||res||^2, c = softplus(curvature), sqrt(c).
// Single 8-value butterfly-reduce round; everything else is scalar algebra.
// ---------------------------------------------------------------------------
__global__ __launch_bounds__(64)
void preprocess_kernel(const float* __restrict__ head,
                       const float* __restrict__ rel,
                       const float* __restrict__ rel_diag,
                       const float* __restrict__ curvature,
                       const float* __restrict__ context,
                       const float* __restrict__ scale_p,
                       float* __restrict__ res,
                       float* __restrict__ row_x2,
                       float* __restrict__ row_c,
                       float* __restrict__ row_sc)
{
    const int row  = blockIdx.x;
    const int lane = threadIdx.x;
    const int base = lane * 8;
    const size_t roff = (size_t)row * D;
    const size_t doff = (size_t)row * 2 * D;

    float hv[8], rv[8], gv[8], fv[8], cxv[8];
    *(float4*)&hv[0]  = *(const float4*)(head + roff + base);
    *(float4*)&hv[4]  = *(const float4*)(head + roff + base + 4);
    *(float4*)&rv[0]  = *(const float4*)(rel + roff + base);
    *(float4*)&rv[4]  = *(const float4*)(rel + roff + base + 4);
    *(float4*)&gv[0]  = *(const float4*)(rel_diag + doff + base);
    *(float4*)&gv[4]  = *(const float4*)(rel_diag + doff + base + 4);
    *(float4*)&fv[0]  = *(const float4*)(rel_diag + doff + D + base);
    *(float4*)&fv[4]  = *(const float4*)(rel_diag + doff + D + base + 4);
    *(float4*)&cxv[0] = *(const float4*)(context + roff + base);
    *(float4*)&cxv[4] = *(const float4*)(context + roff + base + 4);

    // Givens rotation (rq) and reflection (rf) per 2-element pair.
    float rq[8], rf[8];
#pragma unroll
    for (int p = 0; p < 4; ++p) {
        const float x0 = hv[2*p], x1 = hv[2*p+1];
        float g0 = gv[2*p], g1 = gv[2*p+1];
        const float gn = fmaxf(sqrtf(g0*g0 + g1*g1), MIN_NORM);
        g0 /= gn; g1 /= gn;
        rq[2*p]   = g0*x0 - g1*x1;       // rotation
        rq[2*p+1] = g0*x1 + g1*x0;
        float f0 = fv[2*p], f1 = fv[2*p+1];
        const float fn = fmaxf(sqrtf(f0*f0 + f1*f1), MIN_NORM);
        f0 /= fn; f1 /= fn;
        rf[2*p]   = f0*x0 + f1*x1;       // reflection
        rf[2*p+1] = f1*x0 - f0*x1;
    }

    // 8 simultaneous dot products, one reduce round.
    float s0=0,s1=0,s2=0,s3=0,s4=0,s5=0,s6=0,s7=0;
#pragma unroll
    for (int e = 0; e < 8; ++e) {
        s0 += cxv[e]*rf[e];   // ctx . ref_q
        s1 += cxv[e]*rq[e];   // ctx . rot_q
        s2 += rv[e]*rv[e];    // ||rel||^2
        s3 += rf[e]*rv[e];    // ref_q . rel
        s4 += rq[e]*rv[e];    // rot_q . rel
        s5 += rf[e]*rf[e];    // ||ref_q||^2
        s6 += rq[e]*rq[e];    // ||rot_q||^2
        s7 += rf[e]*rq[e];    // ref_q . rot_q
    }
    s0 = wave_sum(s0); s1 = wave_sum(s1); s2 = wave_sum(s2); s3 = wave_sum(s3);
    s4 = wave_sum(s4); s5 = wave_sum(s5); s6 = wave_sum(s6); s7 = wave_sum(s7);

    // c = softplus(curvature), stable
    const float cu = curvature[row];
    const float c  = fmaxf(cu, 0.0f) + log1pf(expf(-fabsf(cu)));
    const float sqc = sqrtf(c);
    const float sc  = scale_p[0];

    // softmax over the 2 candidates (cands = [ref_q, rot_q])
    const float a0 = s0 * sc, a1 = s1 * sc;
    const float mx = fmaxf(a0, a1);
    const float e0 = expf(a0 - mx), e1 = expf(a1 - mx);
    const float w0 = e0 / (e0 + e1);
    const float w1 = 1.0f - w0;

    // att_q norms/dots from the reduced scalars
    const float att2    = fmaxf(w0*w0*s5 + 2.0f*w0*w1*s7 + w1*w1*s6, 0.0f);
    const float attdrel = w0*s3 + w1*s4;
    const float u_att = fmaxf(sqrtf(att2), MIN_NORM);
    const float u_rel = fmaxf(sqrtf(s2), MIN_NORM);

    // expmap0 scale factors: lhs = kl*att_q, rel_h = kr*rel
    const float kl = tanh_clip(sqc * u_att) / (sqc * u_att);
    const float kr = tanh_clip(sqc * u_rel) / (sqc * u_rel);

    const float x2 = kl*kl*att2;
    const float y2 = kr*kr*s2;
    const float xy = kl*kr*attdrel;

    // mobius_add coefficients
    const float Am  = 1.0f + 2.0f*c*xy + c*y2;
    const float Bm  = 1.0f - c*x2;
    const float den = fmaxf(1.0f + 2.0f*c*xy + c*c*x2*y2, MIN_NORM);
    const float inv_den = 1.0f / den;

    float pre[8];
    float r2p = 0.0f;
#pragma unroll
    for (int e = 0; e < 8; ++e) {
        const float attq = w0*rf[e] + w1*rq[e];
        pre[e] = (Am*kl*attq + Bm*kr*rv[e]) * inv_den;
        r2p += pre[e]*pre[e];
    }
    r2p = wave_sum(r2p);

    // project onto the ball
    const float nrm  = fmaxf(sqrtf(r2p), MIN_NORM);
    const float maxn = (1.0f - BALL_EPS) / sqc;
    const float psc  = (nrm > maxn) ? (maxn / nrm) : 1.0f;

    float o[8];
#pragma unroll
    for (int e = 0; e < 8; ++e) o[e] = pre[e] * psc;
    *(float4*)(res + roff + base)     = *(float4*)&o[0];
    *(float4*)(res + roff + base + 4) = *(float4*)&o[4];

    if (lane == 0) {
        row_x2[row] = r2p * psc * psc;
        row_c[row]  = c;
        row_sc[row] = sqc;
    }
}

// ---------------------------------------------------------------------------
// Kernel B: per-tail-row L2 norm (unclamped, as in reference).
// ---------------------------------------------------------------------------
__global__ __launch_bounds__(64)
void vnorm_kernel(const float* __restrict__ tail, float* __restrict__ vnorm)
{
    const int row  = blockIdx.x;
    const int lane = threadIdx.x;
    const size_t roff = (size_t)row * D + lane * 8;
    const float4 v0 = *(const float4*)(tail + roff);
    const float4 v1 = *(const float4*)(tail + roff + 4);
    float s = v0.x*v0.x + v0.y*v0.y + v0.z*v0.z + v0.w*v0.w
            + v1.x*v1.x + v1.y*v1.y + v1.z*v1.z + v1.w*v1.w;
    s = wave_sum(s);
    if (lane == 0) vnorm[row] = sqrtf(s);
}

// ---------------------------------------------------------------------------
// Kernel C: batched f32 GEMM (64x64 tile, BK=16, 4x4 reg blocking) fused with
// the hyperbolic-distance epilogue and bias add.
// LDS tiles stored K-major [BK][BM+4] so compute reads are float4 per lane.
// ---------------------------------------------------------------------------
__global__ __launch_bounds__(256)
void score_kernel(const float* __restrict__ res,
                  const float* __restrict__ tail,
                  const float* __restrict__ vnorm,
                  const float* __restrict__ row_x2,
                  const float* __restrict__ row_c,
                  const float* __restrict__ row_sc,
                  const float* __restrict__ head_bias,
                  const float* __restrict__ tail_bias,
                  float* __restrict__ out,
                  int cs, int ns)
{
    __shared__ float As[BK][BM + 4];
    __shared__ float Bs[BK][BN + 4];

    const int b  = blockIdx.z;
    const int m0 = blockIdx.y * BM;
    const int n0 = blockIdx.x * BN;
    const int tid = threadIdx.x;
    const int tx = tid & 15, ty = tid >> 4;   // 16x16 thread grid -> 4x4 outputs each
    const int lr = tid >> 2, lq = tid & 3;    // loader: row 0..63, quad 0..3

    const float* Ab = res  + ((size_t)b * cs + m0 + lr) * D + lq * 4;
    const float* Bb = tail + ((size_t)b * ns + n0 + lr) * D + lq * 4;

    float acc[4][4] = {};

    for (int k0 = 0; k0 < D; k0 += BK) {
        const float4 av = *(const float4*)(Ab + k0);
        const float4 bv = *(const float4*)(Bb + k0);
        __syncthreads();
        As[lq*4+0][lr] = av.x;
        As[lq*4+1][lr] = av.y;
        As[lq*4+2][lr] = av.z;
        As[lq*4+3][lr] = av.w;
        Bs[lq*4+0][lr] = bv.x;
        Bs[lq*4+1][lr] = bv.y;
        Bs[lq*4+2][lr] = bv.z;
        Bs[lq*4+3][lr] = bv.w;
        __syncthreads();
#pragma unroll
        for (int kk = 0; kk < BK; ++kk) {
            const float4 a  = *(const float4*)&As[kk][ty*4];
            const float4 b4 = *(const float4*)&Bs[kk][tx*4];
            acc[0][0] += a.x*b4.x; acc[0][1] += a.x*b4.y; acc[0][2] += a.x*b4.z; acc[0][3] += a.x*b4.w;
            acc[1][0] += a.y*b4.x; acc[1][1] += a.y*b4.y; acc[1][2] += a.y*b4.z; acc[1][3] += a.y*b4.w;
            acc[2][0] += a.z*b4.x; acc[2][1] += a.z*b4.y; acc[2][2] += a.z*b4.z; acc[2][3] += a.z*b4.w;
            acc[3][0] += a.w*b4.x; acc[3][1] += a.w*b4.y; acc[3][2] += a.w*b4.z; acc[3][3] += a.w*b4.w;
        }
    }

    // Fused hyperbolic-distance epilogue.
    const int gm = b * cs + m0 + ty * 4;   // global query row base
    const int gn = b * ns + n0 + tx * 4;   // global tail row base
#pragma unroll
    for (int i = 0; i < 4; ++i) {
        const int gi = gm + i;
        const float x2  = row_x2[gi];
        const float cc  = row_c[gi];
        const float scq = row_sc[gi];
        const float hb  = head_bias[gi];
        float ov[4];
#pragma unroll
        for (int j = 0; j < 4; ++j) {
            const int gj = gn + j;
            const float vn = vnorm[gj];
            const float xv = acc[i][j] / vn;
            const float g  = tanh_clip(scq * vn) / scq;              // gamma
            const float c1 = 1.0f - 2.0f*cc*g*xv + cc*g*g;
            const float c2 = 1.0f - cc*x2;
            const float num = sqrtf(fmaxf(c1*c1*x2 + c2*c2*g*g - 2.0f*c1*c2*g*xv, 0.0f));
            const float den = fmaxf(1.0f - 2.0f*cc*g*xv + cc*cc*g*g*x2, MIN_NORM);
            float t = scq * num / den;
            t = fminf(fmaxf(t, -1.0f + 1e-5f), 1.0f - 1e-5f);
            const float dist = (2.0f / scq) * (0.5f * logf((1.0f + t) / (1.0f - t)));
            ov[j] = -dist*dist + hb + tail_bias[gj];
        }
        float4 o4 = make_float4(ov[0], ov[1], ov[2], ov[3]);
        *(float4*)(out + (size_t)gi * ns + n0 + tx*4) = o4;
    }
}

// ---------------------------------------------------------------------------
extern "C" void kernel_launch(void* const* d_in, const int* in_sizes, int n_in,
                              void* d_out, int out_size, void* d_ws, size_t ws_size,
                              hipStream_t stream)
{
    const float* head      = (const float*)d_in[0];
    const float* head_bias = (const float*)d_in[1];
    const float* rel       = (const float*)d_in[2];
    const float* rel_diag  = (const float*)d_in[3];
    const float* curvature = (const float*)d_in[4];
    const float* context   = (const float*)d_in[5];
    const float* scale     = (const float*)d_in[6];
    const float* tail      = (const float*)d_in[7];
    const float* tail_bias = (const float*)d_in[8];

    const int B  = in_sizes[1];        // 16384 (head_bias is (B,1))
    const int T  = in_sizes[8];        // 16384 (tail_bias is (T,1))
    const int ns = out_size / B;       // 1024
    const int nc = T / ns;             // 16
    const int cs = B / nc;             // 1024

    // workspace layout: res (B*D) | x2 (B) | c (B) | sqc (B) | vnorm (T)
    float* res     = (float*)d_ws;
    float* row_x2  = res + (size_t)B * D;
    float* row_c   = row_x2 + B;
    float* row_sc  = row_c + B;
    float* vnormb  = row_sc + B;

    preprocess_kernel<<<B, 64, 0, stream>>>(head, rel, rel_diag, curvature, context,
                                            scale, res, row_x2, row_c, row_sc);
    vnorm_kernel<<<T, 64, 0, stream>>>(tail, vnormb);

    dim3 grid(ns / BN, cs / BM, nc);
    score_kernel<<<grid, 256, 0, stream>>>(res, tail, vnormb, row_x2, row_c, row_sc,
                                           head_bias, tail_bias, (float*)d_out, cs, ns);
}

// Round 2
// 154.050 us; speedup vs baseline: 2.1173x; 2.1173x over previous
//
#include <hip/hip_runtime.h>
#include <math.h>

#define DEV static __device__ __forceinline__

constexpr float MIN_NORM = 1e-15f;
constexpr float BALL_EPS = 1e-5f;
constexpr int D = 512;          // feature dim (fixed by problem)

typedef float f32x4 __attribute__((ext_vector_type(4)));
typedef short short8v __attribute__((ext_vector_type(8)));
typedef unsigned short ushort8v __attribute__((ext_vector_type(8)));

DEV float wave_sum(float v) {
#pragma unroll
    for (int o = 32; o > 0; o >>= 1) v += __shfl_xor(v, o, 64);
    return v;
}

DEV float tanh_clip(float x) {
    x = fminf(fmaxf(x, -15.0f), 15.0f);
    return tanhf(x);
}

// bf16 split helpers (RNE)
DEV unsigned short f2bf(float f) {
    unsigned int u = __float_as_uint(f);
    u = (u + 0x7FFFu + ((u >> 16) & 1u)) >> 16;
    return (unsigned short)u;
}
DEV float bf2f(unsigned short h) { return __uint_as_float(((unsigned int)h) << 16); }

// ---------------------------------------------------------------------------
// Kernel A: per-row preprocessing. One wave per row, 8 elems/lane.
// Emits res split into bf16 hi/lo (for the MFMA GEMM) + per-row scalars.
// ---------------------------------------------------------------------------
__global__ __launch_bounds__(64)
void preprocess_kernel(const float* __restrict__ head,
                       const float* __restrict__ rel,
                       const float* __restrict__ rel_diag,
                       const float* __restrict__ curvature,
                       const float* __restrict__ context,
                       const float* __restrict__ scale_p,
                       unsigned short* __restrict__ Ah,
                       unsigned short* __restrict__ Al,
                       float* __restrict__ row_x2,
                       float* __restrict__ row_c,
                       float* __restrict__ row_sc)
{
    const int row  = blockIdx.x;
    const int lane = threadIdx.x;
    const int base = lane * 8;
    const size_t roff = (size_t)row * D;
    const size_t doff = (size_t)row * 2 * D;

    float hv[8], rv[8], gv[8], fv[8], cxv[8];
    *(float4*)&hv[0]  = *(const float4*)(head + roff + base);
    *(float4*)&hv[4]  = *(const float4*)(head + roff + base + 4);
    *(float4*)&rv[0]  = *(const float4*)(rel + roff + base);
    *(float4*)&rv[4]  = *(const float4*)(rel + roff + base + 4);
    *(float4*)&gv[0]  = *(const float4*)(rel_diag + doff + base);
    *(float4*)&gv[4]  = *(const float4*)(rel_diag + doff + base + 4);
    *(float4*)&fv[0]  = *(const float4*)(rel_diag + doff + D + base);
    *(float4*)&fv[4]  = *(const float4*)(rel_diag + doff + D + base + 4);
    *(float4*)&cxv[0] = *(const float4*)(context + roff + base);
    *(float4*)&cxv[4] = *(const float4*)(context + roff + base + 4);

    float rq[8], rf[8];
#pragma unroll
    for (int p = 0; p < 4; ++p) {
        const float x0 = hv[2*p], x1 = hv[2*p+1];
        float g0 = gv[2*p], g1 = gv[2*p+1];
        const float gn = fmaxf(sqrtf(g0*g0 + g1*g1), MIN_NORM);
        g0 /= gn; g1 /= gn;
        rq[2*p]   = g0*x0 - g1*x1;       // rotation
        rq[2*p+1] = g0*x1 + g1*x0;
        float f0 = fv[2*p], f1 = fv[2*p+1];
        const float fn = fmaxf(sqrtf(f0*f0 + f1*f1), MIN_NORM);
        f0 /= fn; f1 /= fn;
        rf[2*p]   = f0*x0 + f1*x1;       // reflection
        rf[2*p+1] = f1*x0 - f0*x1;
    }

    float s0=0,s1=0,s2=0,s3=0,s4=0,s5=0,s6=0,s7=0;
#pragma unroll
    for (int e = 0; e < 8; ++e) {
        s0 += cxv[e]*rf[e];   s1 += cxv[e]*rq[e];
        s2 += rv[e]*rv[e];    s3 += rf[e]*rv[e];
        s4 += rq[e]*rv[e];    s5 += rf[e]*rf[e];
        s6 += rq[e]*rq[e];    s7 += rf[e]*rq[e];
    }
    s0 = wave_sum(s0); s1 = wave_sum(s1); s2 = wave_sum(s2); s3 = wave_sum(s3);
    s4 = wave_sum(s4); s5 = wave_sum(s5); s6 = wave_sum(s6); s7 = wave_sum(s7);

    const float cu = curvature[row];
    const float c  = fmaxf(cu, 0.0f) + log1pf(expf(-fabsf(cu)));
    const float sqc = sqrtf(c);
    const float sc  = scale_p[0];

    const float a0 = s0 * sc, a1 = s1 * sc;
    const float mx = fmaxf(a0, a1);
    const float e0 = expf(a0 - mx), e1 = expf(a1 - mx);
    const float w0 = e0 / (e0 + e1);
    const float w1 = 1.0f - w0;

    const float att2    = fmaxf(w0*w0*s5 + 2.0f*w0*w1*s7 + w1*w1*s6, 0.0f);
    const float attdrel = w0*s3 + w1*s4;
    const float u_att = fmaxf(sqrtf(att2), MIN_NORM);
    const float u_rel = fmaxf(sqrtf(s2), MIN_NORM);

    const float kl = tanh_clip(sqc * u_att) / (sqc * u_att);
    const float kr = tanh_clip(sqc * u_rel) / (sqc * u_rel);

    const float x2 = kl*kl*att2;
    const float y2 = kr*kr*s2;
    const float xy = kl*kr*attdrel;

    const float Am  = 1.0f + 2.0f*c*xy + c*y2;
    const float Bm  = 1.0f - c*x2;
    const float den = fmaxf(1.0f + 2.0f*c*xy + c*c*x2*y2, MIN_NORM);
    const float inv_den = 1.0f / den;

    float pre[8];
    float r2p = 0.0f;
#pragma unroll
    for (int e = 0; e < 8; ++e) {
        const float attq = w0*rf[e] + w1*rq[e];
        pre[e] = (Am*kl*attq + Bm*kr*rv[e]) * inv_den;
        r2p += pre[e]*pre[e];
    }
    r2p = wave_sum(r2p);

    const float nrm  = fmaxf(sqrtf(r2p), MIN_NORM);
    const float maxn = (1.0f - BALL_EPS) / sqc;
    const float psc  = (nrm > maxn) ? (maxn / nrm) : 1.0f;

    ushort8v hi, lo;
#pragma unroll
    for (int e = 0; e < 8; ++e) {
        const float o = pre[e] * psc;
        const unsigned short hb_ = f2bf(o);
        hi[e] = hb_;
        lo[e] = f2bf(o - bf2f(hb_));
    }
    *(ushort8v*)(Ah + roff + base) = hi;
    *(ushort8v*)(Al + roff + base) = lo;

    if (lane == 0) {
        row_x2[row] = r2p * psc * psc;
        row_c[row]  = c;
        row_sc[row] = sqc;
    }
}

// ---------------------------------------------------------------------------
// Kernel B: per-tail-row L2 norm + bf16 hi/lo split of tail.
// ---------------------------------------------------------------------------
__global__ __launch_bounds__(64)
void tailprep_kernel(const float* __restrict__ tail,
                     unsigned short* __restrict__ Bh,
                     unsigned short* __restrict__ Bl,
                     float* __restrict__ vnorm)
{
    const int row  = blockIdx.x;
    const int lane = threadIdx.x;
    const size_t roff = (size_t)row * D + lane * 8;
    float v[8];
    *(float4*)&v[0] = *(const float4*)(tail + roff);
    *(float4*)&v[4] = *(const float4*)(tail + roff + 4);
    float s = 0.0f;
    ushort8v hi, lo;
#pragma unroll
    for (int e = 0; e < 8; ++e) {
        s += v[e]*v[e];
        const unsigned short hb_ = f2bf(v[e]);
        hi[e] = hb_;
        lo[e] = f2bf(v[e] - bf2f(hb_));
    }
    s = wave_sum(s);
    *(ushort8v*)(Bh + roff) = hi;
    *(ushort8v*)(Bl + roff) = lo;
    if (lane == 0) vnorm[row] = sqrtf(s);
}

// ---------------------------------------------------------------------------
// Kernel C: split-bf16 MFMA GEMM (128x128 tile, BK=64, 4 waves, 3 passes:
// Ah*Bh + Ah*Bl + Al*Bh) fused with the hyperbolic-distance epilogue.
// LDS: linear dest for global_load_lds + XOR-swizzled source/read (rule #21):
// chunk' = chunk ^ (row&7), 16B chunks, 128B rows -> ~2-way conflicts max.
// ---------------------------------------------------------------------------
__global__ __launch_bounds__(256)
void score_kernel(const unsigned short* __restrict__ Ah,
                  const unsigned short* __restrict__ Al,
                  const unsigned short* __restrict__ Bh,
                  const unsigned short* __restrict__ Bl,
                  const float* __restrict__ vnorm,
                  const float* __restrict__ row_x2,
                  const float* __restrict__ row_c,
                  const float* __restrict__ row_sc,
                  const float* __restrict__ head_bias,
                  const float* __restrict__ tail_bias,
                  float* __restrict__ out,
                  int cs, int ns)
{
    __shared__ __align__(16) char smem[32768];   // A tile 16KB | B tile 16KB

    const int bz = blockIdx.z;
    const int m0 = blockIdx.y * 128;
    const int n0 = blockIdx.x * 128;
    const int tid  = threadIdx.x;
    const int lane = tid & 63;
    const int w    = tid >> 6;
    const int wr   = w >> 1, wc = w & 1;          // 2x2 wave grid, 64x64 each
    const int lrow = lane & 15, lg = lane >> 4;   // fragment row / k-group

    f32x4 acc[4][4];
#pragma unroll
    for (int i = 0; i < 4; ++i)
#pragma unroll
        for (int j = 0; j < 4; ++j) acc[i][j] = f32x4{0.f, 0.f, 0.f, 0.f};

    const size_t Aoff = (size_t)(bz * cs + m0) * D;
    const size_t Boff = (size_t)(bz * ns + n0) * D;

    for (int p = 0; p < 3; ++p) {
        const unsigned short* Ag = ((p == 2) ? Al : Ah) + Aoff;
        const unsigned short* Bg = ((p == 1) ? Bl : Bh) + Boff;
        for (int k0 = 0; k0 < D; k0 += 64) {
            // ---- stage A & B tiles: 128 rows x 64 bf16 = 16KB each ----
            // linear LDS chunk L -> (row r, chunk c); global source chunk c^(r&7)
#pragma unroll
            for (int it = 0; it < 4; ++it) {
                const int L = it * 256 + tid;
                const int r = L >> 3, c = L & 7;
                const int kc = c ^ (r & 7);
                __builtin_amdgcn_global_load_lds(
                    (const __attribute__((address_space(1))) unsigned int*)(Ag + (size_t)r * D + k0 + kc * 8),
                    (__attribute__((address_space(3))) unsigned int*)(smem + L * 16),
                    16, 0, 0);
            }
#pragma unroll
            for (int it = 0; it < 4; ++it) {
                const int L = it * 256 + tid;
                const int r = L >> 3, c = L & 7;
                const int kc = c ^ (r & 7);
                __builtin_amdgcn_global_load_lds(
                    (const __attribute__((address_space(1))) unsigned int*)(Bg + (size_t)r * D + k0 + kc * 8),
                    (__attribute__((address_space(3))) unsigned int*)(smem + 16384 + L * 16),
                    16, 0, 0);
            }
            __syncthreads();   // drains vmcnt(0) before barrier

            // ---- compute: 2 K-slices x 4x4 fragments ----
#pragma unroll
            for (int kk = 0; kk < 2; ++kk) {
                short8v af[4], bfr[4];
#pragma unroll
                for (int i = 0; i < 4; ++i) {
                    const int row = wr * 64 + i * 16 + lrow;
                    const int ch  = (kk * 4 + lg) ^ (lrow & 7);
                    af[i] = *(const short8v*)(smem + row * 128 + ch * 16);
                }
#pragma unroll
                for (int j = 0; j < 4; ++j) {
                    const int row = wc * 64 + j * 16 + lrow;
                    const int ch  = (kk * 4 + lg) ^ (lrow & 7);
                    bfr[j] = *(const short8v*)(smem + 16384 + row * 128 + ch * 16);
                }
#pragma unroll
                for (int i = 0; i < 4; ++i)
#pragma unroll
                    for (int j = 0; j < 4; ++j)
                        acc[i][j] = __builtin_amdgcn_mfma_f32_16x16x32_bf16(
                            af[i], bfr[j], acc[i][j], 0, 0, 0);
            }
            __syncthreads();
        }
    }

    // ---- fused hyperbolic-distance epilogue ----
    // C/D layout (m89-verified): col = lane&15, row = (lane>>4)*4 + q
    const int nbase = n0 + wc * 64 + lrow;
    float rvn[4], vnv[4], tb[4];
#pragma unroll
    for (int j = 0; j < 4; ++j) {
        const int gn = bz * ns + nbase + j * 16;
        const float vn = vnorm[gn];
        vnv[j] = vn;
        rvn[j] = 1.0f / vn;
        tb[j]  = tail_bias[gn];
    }
#pragma unroll
    for (int i = 0; i < 4; ++i) {
#pragma unroll
        for (int q = 0; q < 4; ++q) {
            const int gm = bz * cs + m0 + wr * 64 + i * 16 + lg * 4 + q;
            const float x2  = row_x2[gm];
            const float cc  = row_c[gm];
            const float scq = row_sc[gm];
            const float hb  = head_bias[gm];
            const float rscq = 1.0f / scq;
            float* orow = out + (size_t)gm * ns + nbase;
#pragma unroll
            for (int j = 0; j < 4; ++j) {
                const float xv = acc[i][j][q] * rvn[j];
                float xx = fminf(scq * vnv[j], 15.0f);           // x >= 0 always
                const float ey = __expf(2.0f * xx);
                const float g  = (1.0f - 2.0f / (ey + 1.0f)) * rscq;  // tanh/sqc
                const float c1 = 1.0f - 2.0f*cc*g*xv + cc*g*g;
                const float c2 = 1.0f - cc*x2;
                const float num = sqrtf(fmaxf(c1*c1*x2 + c2*c2*g*g - 2.0f*c1*c2*g*xv, 0.0f));
                const float den = fmaxf(1.0f - 2.0f*cc*g*xv + cc*cc*g*g*x2, MIN_NORM);
                float t = scq * num * __builtin_amdgcn_rcpf(den);
                t = fminf(t, 1.0f - 1e-5f);                      // t >= 0 always
                const float ath = 0.5f * __logf((1.0f + t) * __builtin_amdgcn_rcpf(1.0f - t));
                const float dist = 2.0f * rscq * ath;
                orow[j * 16] = -dist * dist + hb + tb[j];
            }
        }
    }
}

// ---------------------------------------------------------------------------
extern "C" void kernel_launch(void* const* d_in, const int* in_sizes, int n_in,
                              void* d_out, int out_size, void* d_ws, size_t ws_size,
                              hipStream_t stream)
{
    const float* head      = (const float*)d_in[0];
    const float* head_bias = (const float*)d_in[1];
    const float* rel       = (const float*)d_in[2];
    const float* rel_diag  = (const float*)d_in[3];
    const float* curvature = (const float*)d_in[4];
    const float* context   = (const float*)d_in[5];
    const float* scale     = (const float*)d_in[6];
    const float* tail      = (const float*)d_in[7];
    const float* tail_bias = (const float*)d_in[8];

    const int B  = in_sizes[1];        // 16384
    const int T  = in_sizes[8];        // 16384
    const int ns = out_size / B;       // 1024
    const int nc = T / ns;             // 16
    const int cs = B / nc;             // 1024

    // ws layout: Ah | Al | Bh | Bl (bf16) then f32 scalars
    unsigned short* Ah = (unsigned short*)d_ws;
    unsigned short* Al = Ah + (size_t)B * D;
    unsigned short* Bh = Al + (size_t)B * D;
    unsigned short* Bl = Bh + (size_t)T * D;
    float* row_x2 = (float*)(Bl + (size_t)T * D);
    float* row_c  = row_x2 + B;
    float* row_sc = row_c + B;
    float* vnormb = row_sc + B;

    preprocess_kernel<<<B, 64, 0, stream>>>(head, rel, rel_diag, curvature, context,
                                            scale, Ah, Al, row_x2, row_c, row_sc);
    tailprep_kernel<<<T, 64, 0, stream>>>(tail, Bh, Bl, vnormb);

    dim3 grid(ns / 128, cs / 128, nc);
    score_kernel<<<grid, 256, 0, stream>>>(Ah, Al, Bh, Bl, vnormb, row_x2, row_c, row_sc,
                                           head_bias, tail_bias, (float*)d_out, cs, ns);
}

// Round 3
// 148.495 us; speedup vs baseline: 2.1965x; 1.0374x over previous
//
#include <hip/hip_runtime.h>
#include <math.h>

#define DEV static __device__ __forceinline__

constexpr float MIN_NORM = 1e-15f;
constexpr float BALL_EPS = 1e-5f;
constexpr int D = 512;          // feature dim (fixed by problem)

typedef float f32x4 __attribute__((ext_vector_type(4)));
typedef short short8v __attribute__((ext_vector_type(8)));
typedef unsigned short ushort8v __attribute__((ext_vector_type(8)));

DEV float wave_sum(float v) {
#pragma unroll
    for (int o = 32; o > 0; o >>= 1) v += __shfl_xor(v, o, 64);
    return v;
}

DEV float tanh_clip(float x) {
    x = fminf(fmaxf(x, -15.0f), 15.0f);
    return tanhf(x);
}

// bf16 split helpers (RNE)
DEV unsigned short f2bf(float f) {
    unsigned int u = __float_as_uint(f);
    u = (u + 0x7FFFu + ((u >> 16) & 1u)) >> 16;
    return (unsigned short)u;
}
DEV float bf2f(unsigned short h) { return __uint_as_float(((unsigned int)h) << 16); }

// ---------------------------------------------------------------------------
// Kernel A: per-row preprocessing. One wave per row, 8 elems/lane.
// Emits res split into bf16 hi/lo (for the MFMA GEMM) + per-row scalars.
// ---------------------------------------------------------------------------
__global__ __launch_bounds__(64)
void preprocess_kernel(const float* __restrict__ head,
                       const float* __restrict__ rel,
                       const float* __restrict__ rel_diag,
                       const float* __restrict__ curvature,
                       const float* __restrict__ context,
                       const float* __restrict__ scale_p,
                       unsigned short* __restrict__ Ah,
                       unsigned short* __restrict__ Al,
                       float* __restrict__ row_x2,
                       float* __restrict__ row_c,
                       float* __restrict__ row_sc)
{
    const int row  = blockIdx.x;
    const int lane = threadIdx.x;
    const int base = lane * 8;
    const size_t roff = (size_t)row * D;
    const size_t doff = (size_t)row * 2 * D;

    float hv[8], rv[8], gv[8], fv[8], cxv[8];
    *(float4*)&hv[0]  = *(const float4*)(head + roff + base);
    *(float4*)&hv[4]  = *(const float4*)(head + roff + base + 4);
    *(float4*)&rv[0]  = *(const float4*)(rel + roff + base);
    *(float4*)&rv[4]  = *(const float4*)(rel + roff + base + 4);
    *(float4*)&gv[0]  = *(const float4*)(rel_diag + doff + base);
    *(float4*)&gv[4]  = *(const float4*)(rel_diag + doff + base + 4);
    *(float4*)&fv[0]  = *(const float4*)(rel_diag + doff + D + base);
    *(float4*)&fv[4]  = *(const float4*)(rel_diag + doff + D + base + 4);
    *(float4*)&cxv[0] = *(const float4*)(context + roff + base);
    *(float4*)&cxv[4] = *(const float4*)(context + roff + base + 4);

    float rq[8], rf[8];
#pragma unroll
    for (int p = 0; p < 4; ++p) {
        const float x0 = hv[2*p], x1 = hv[2*p+1];
        float g0 = gv[2*p], g1 = gv[2*p+1];
        const float gn = fmaxf(sqrtf(g0*g0 + g1*g1), MIN_NORM);
        g0 /= gn; g1 /= gn;
        rq[2*p]   = g0*x0 - g1*x1;       // rotation
        rq[2*p+1] = g0*x1 + g1*x0;
        float f0 = fv[2*p], f1 = fv[2*p+1];
        const float fn = fmaxf(sqrtf(f0*f0 + f1*f1), MIN_NORM);
        f0 /= fn; f1 /= fn;
        rf[2*p]   = f0*x0 + f1*x1;       // reflection
        rf[2*p+1] = f1*x0 - f0*x1;
    }

    float s0=0,s1=0,s2=0,s3=0,s4=0,s5=0,s6=0,s7=0;
#pragma unroll
    for (int e = 0; e < 8; ++e) {
        s0 += cxv[e]*rf[e];   s1 += cxv[e]*rq[e];
        s2 += rv[e]*rv[e];    s3 += rf[e]*rv[e];
        s4 += rq[e]*rv[e];    s5 += rf[e]*rf[e];
        s6 += rq[e]*rq[e];    s7 += rf[e]*rq[e];
    }
    s0 = wave_sum(s0); s1 = wave_sum(s1); s2 = wave_sum(s2); s3 = wave_sum(s3);
    s4 = wave_sum(s4); s5 = wave_sum(s5); s6 = wave_sum(s6); s7 = wave_sum(s7);

    const float cu = curvature[row];
    const float c  = fmaxf(cu, 0.0f) + log1pf(expf(-fabsf(cu)));
    const float sqc = sqrtf(c);
    const float sc  = scale_p[0];

    const float a0 = s0 * sc, a1 = s1 * sc;
    const float mx = fmaxf(a0, a1);
    const float e0 = expf(a0 - mx), e1 = expf(a1 - mx);
    const float w0 = e0 / (e0 + e1);
    const float w1 = 1.0f - w0;

    const float att2    = fmaxf(w0*w0*s5 + 2.0f*w0*w1*s7 + w1*w1*s6, 0.0f);
    const float attdrel = w0*s3 + w1*s4;
    const float u_att = fmaxf(sqrtf(att2), MIN_NORM);
    const float u_rel = fmaxf(sqrtf(s2), MIN_NORM);

    const float kl = tanh_clip(sqc * u_att) / (sqc * u_att);
    const float kr = tanh_clip(sqc * u_rel) / (sqc * u_rel);

    const float x2 = kl*kl*att2;
    const float y2 = kr*kr*s2;
    const float xy = kl*kr*attdrel;

    const float Am  = 1.0f + 2.0f*c*xy + c*y2;
    const float Bm  = 1.0f - c*x2;
    const float den = fmaxf(1.0f + 2.0f*c*xy + c*c*x2*y2, MIN_NORM);
    const float inv_den = 1.0f / den;

    float pre[8];
    float r2p = 0.0f;
#pragma unroll
    for (int e = 0; e < 8; ++e) {
        const float attq = w0*rf[e] + w1*rq[e];
        pre[e] = (Am*kl*attq + Bm*kr*rv[e]) * inv_den;
        r2p += pre[e]*pre[e];
    }
    r2p = wave_sum(r2p);

    const float nrm  = fmaxf(sqrtf(r2p), MIN_NORM);
    const float maxn = (1.0f - BALL_EPS) / sqc;
    const float psc  = (nrm > maxn) ? (maxn / nrm) : 1.0f;

    ushort8v hi, lo;
#pragma unroll
    for (int e = 0; e < 8; ++e) {
        const float o = pre[e] * psc;
        const unsigned short hb_ = f2bf(o);
        hi[e] = hb_;
        lo[e] = f2bf(o - bf2f(hb_));
    }
    *(ushort8v*)(Ah + roff + base) = hi;
    *(ushort8v*)(Al + roff + base) = lo;

    if (lane == 0) {
        row_x2[row] = r2p * psc * psc;
        row_c[row]  = c;
        row_sc[row] = sqc;
    }
}

// ---------------------------------------------------------------------------
// Kernel B: per-tail-row L2 norm + bf16 hi/lo split of tail.
// ---------------------------------------------------------------------------
__global__ __launch_bounds__(64)
void tailprep_kernel(const float* __restrict__ tail,
                     unsigned short* __restrict__ Bh,
                     unsigned short* __restrict__ Bl,
                     float* __restrict__ vnorm)
{
    const int row  = blockIdx.x;
    const int lane = threadIdx.x;
    const size_t roff = (size_t)row * D + lane * 8;
    float v[8];
    *(float4*)&v[0] = *(const float4*)(tail + roff);
    *(float4*)&v[4] = *(const float4*)(tail + roff + 4);
    float s = 0.0f;
    ushort8v hi, lo;
#pragma unroll
    for (int e = 0; e < 8; ++e) {
        s += v[e]*v[e];
        const unsigned short hb_ = f2bf(v[e]);
        hi[e] = hb_;
        lo[e] = f2bf(v[e] - bf2f(hb_));
    }
    s = wave_sum(s);
    *(ushort8v*)(Bh + roff) = hi;
    *(ushort8v*)(Bl + roff) = lo;
    if (lane == 0) vnorm[row] = sqrtf(s);
}

// ---------------------------------------------------------------------------
// Kernel C: fused tri-product split-bf16 MFMA GEMM.
// 128x128 tile, 4 waves (64x64 each), BK=32.
// LDS rows pack hi+lo: 128 rows x 8 chunks of 16B (chunks 0-3 = hi k0..k31,
// chunks 4-7 = lo k0..k31), XOR involution chunk^=(row&7) on BOTH the
// global-source side (staging) and the read side (rule #21).
// Per k0: stage 32KB, read 16 b128/wave, 48 MFMA/wave (Ah*Bh+Ah*Bl+Al*Bh).
// ---------------------------------------------------------------------------
__global__ __launch_bounds__(256)
void score_kernel(const unsigned short* __restrict__ Ah,
                  const unsigned short* __restrict__ Al,
                  const unsigned short* __restrict__ Bh,
                  const unsigned short* __restrict__ Bl,
                  const float* __restrict__ vnorm,
                  const float* __restrict__ row_x2,
                  const float* __restrict__ row_c,
                  const float* __restrict__ row_sc,
                  const float* __restrict__ head_bias,
                  const float* __restrict__ tail_bias,
                  float* __restrict__ out,
                  int cs, int ns)
{
    __shared__ __align__(16) char smem[32768];   // A 16KB | B 16KB

    const int bz = blockIdx.z;
    const int m0 = blockIdx.y * 128;
    const int n0 = blockIdx.x * 128;
    const int tid  = threadIdx.x;
    const int lane = tid & 63;
    const int w    = tid >> 6;
    const int wr   = w >> 1, wc = w & 1;          // 2x2 wave grid, 64x64 each
    const int lrow = lane & 15, lg = lane >> 4;   // fragment row / k-group

    f32x4 acc[4][4];
#pragma unroll
    for (int i = 0; i < 4; ++i)
#pragma unroll
        for (int j = 0; j < 4; ++j) acc[i][j] = f32x4{0.f, 0.f, 0.f, 0.f};

    const size_t Aoff = (size_t)(bz * cs + m0) * D;
    const size_t Boff = (size_t)(bz * ns + n0) * D;

    for (int k0 = 0; k0 < D; k0 += 32) {
        // ---- stage combined hi/lo tiles: 2 x (128 rows x 128B) = 32KB ----
        // LDS slot (r, s) holds logical chunk s^(r&7); chunks 0-3 hi, 4-7 lo.
#pragma unroll
        for (int it = 0; it < 4; ++it) {
            const int L = it * 256 + tid;
            const int r = L >> 3, s = L & 7;
            const int kc = s ^ (r & 7);
            const unsigned short* src = (kc < 4)
                ? Ah + Aoff + (size_t)r * D + k0 + kc * 8
                : Al + Aoff + (size_t)r * D + k0 + (kc - 4) * 8;
            __builtin_amdgcn_global_load_lds(
                (const __attribute__((address_space(1))) unsigned int*)src,
                (__attribute__((address_space(3))) unsigned int*)(smem + L * 16),
                16, 0, 0);
        }
#pragma unroll
        for (int it = 0; it < 4; ++it) {
            const int L = it * 256 + tid;
            const int r = L >> 3, s = L & 7;
            const int kc = s ^ (r & 7);
            const unsigned short* src = (kc < 4)
                ? Bh + Boff + (size_t)r * D + k0 + kc * 8
                : Bl + Boff + (size_t)r * D + k0 + (kc - 4) * 8;
            __builtin_amdgcn_global_load_lds(
                (const __attribute__((address_space(1))) unsigned int*)src,
                (__attribute__((address_space(3))) unsigned int*)(smem + 16384 + L * 16),
                16, 0, 0);
        }
        __syncthreads();   // drains vmcnt(0) before barrier

        // ---- read fragments once, use hi twice ----
        short8v ah[4], al[4], bh[4], bl[4];
#pragma unroll
        for (int i = 0; i < 4; ++i) {
            const int r = wr * 64 + i * 16 + lrow;
            const char* rowp = smem + r * 128;
            ah[i] = *(const short8v*)(rowp + ((lg    ) ^ (r & 7)) * 16);
            al[i] = *(const short8v*)(rowp + ((lg + 4) ^ (r & 7)) * 16);
        }
#pragma unroll
        for (int j = 0; j < 4; ++j) {
            const int r = wc * 64 + j * 16 + lrow;
            const char* rowp = smem + 16384 + r * 128;
            bh[j] = *(const short8v*)(rowp + ((lg    ) ^ (r & 7)) * 16);
            bl[j] = *(const short8v*)(rowp + ((lg + 4) ^ (r & 7)) * 16);
        }

        // ---- 48 MFMA: x.v = Ah*Bh + Ah*Bl + Al*Bh (Al*Bl dropped ~2^-18) --
#pragma unroll
        for (int i = 0; i < 4; ++i)
#pragma unroll
            for (int j = 0; j < 4; ++j) {
                acc[i][j] = __builtin_amdgcn_mfma_f32_16x16x32_bf16(ah[i], bh[j], acc[i][j], 0, 0, 0);
                acc[i][j] = __builtin_amdgcn_mfma_f32_16x16x32_bf16(ah[i], bl[j], acc[i][j], 0, 0, 0);
                acc[i][j] = __builtin_amdgcn_mfma_f32_16x16x32_bf16(al[i], bh[j], acc[i][j], 0, 0, 0);
            }
        __syncthreads();
    }

    // ---- fused hyperbolic-distance epilogue ----
    // C/D layout (m89-verified): col = lane&15, row = (lane>>4)*4 + q
    const int nbase = n0 + wc * 64 + lrow;
    float rvn[4], vnv[4], tb[4];
#pragma unroll
    for (int j = 0; j < 4; ++j) {
        const int gn = bz * ns + nbase + j * 16;
        const float vn = vnorm[gn];
        vnv[j] = vn;
        rvn[j] = 1.0f / vn;
        tb[j]  = tail_bias[gn];
    }
#pragma unroll
    for (int i = 0; i < 4; ++i) {
#pragma unroll
        for (int q = 0; q < 4; ++q) {
            const int gm = bz * cs + m0 + wr * 64 + i * 16 + lg * 4 + q;
            const float x2  = row_x2[gm];
            const float cc  = row_c[gm];
            const float scq = row_sc[gm];
            const float hb  = head_bias[gm];
            const float rscq = 1.0f / scq;
            float* orow = out + (size_t)gm * ns + nbase;
#pragma unroll
            for (int j = 0; j < 4; ++j) {
                const float xv = acc[i][j][q] * rvn[j];
                float xx = fminf(scq * vnv[j], 15.0f);           // x >= 0 always
                const float ey = __expf(2.0f * xx);
                const float g  = (1.0f - 2.0f / (ey + 1.0f)) * rscq;  // tanh/sqc
                const float c1 = 1.0f - 2.0f*cc*g*xv + cc*g*g;
                const float c2 = 1.0f - cc*x2;
                const float num = sqrtf(fmaxf(c1*c1*x2 + c2*c2*g*g - 2.0f*c1*c2*g*xv, 0.0f));
                const float den = fmaxf(1.0f - 2.0f*cc*g*xv + cc*cc*g*g*x2, MIN_NORM);
                float t = scq * num * __builtin_amdgcn_rcpf(den);
                t = fminf(t, 1.0f - 1e-5f);                      // t >= 0 always
                const float ath = 0.5f * __logf((1.0f + t) * __builtin_amdgcn_rcpf(1.0f - t));
                const float dist = 2.0f * rscq * ath;
                orow[j * 16] = -dist * dist + hb + tb[j];
            }
        }
    }
}

// ---------------------------------------------------------------------------
extern "C" void kernel_launch(void* const* d_in, const int* in_sizes, int n_in,
                              void* d_out, int out_size, void* d_ws, size_t ws_size,
                              hipStream_t stream)
{
    const float* head      = (const float*)d_in[0];
    const float* head_bias = (const float*)d_in[1];
    const float* rel       = (const float*)d_in[2];
    const float* rel_diag  = (const float*)d_in[3];
    const float* curvature = (const float*)d_in[4];
    const float* context   = (const float*)d_in[5];
    const float* scale     = (const float*)d_in[6];
    const float* tail      = (const float*)d_in[7];
    const float* tail_bias = (const float*)d_in[8];

    const int B  = in_sizes[1];        // 16384
    const int T  = in_sizes[8];        // 16384
    const int ns = out_size / B;       // 1024
    const int nc = T / ns;             // 16
    const int cs = B / nc;             // 1024

    // ws layout: Ah | Al | Bh | Bl (bf16) then f32 scalars
    unsigned short* Ah = (unsigned short*)d_ws;
    unsigned short* Al = Ah + (size_t)B * D;
    unsigned short* Bh = Al + (size_t)B * D;
    unsigned short* Bl = Bh + (size_t)T * D;
    float* row_x2 = (float*)(Bl + (size_t)T * D);
    float* row_c  = row_x2 + B;
    float* row_sc = row_c + B;
    float* vnormb = row_sc + B;

    preprocess_kernel<<<B, 64, 0, stream>>>(head, rel, rel_diag, curvature, context,
                                            scale, Ah, Al, row_x2, row_c, row_sc);
    tailprep_kernel<<<T, 64, 0, stream>>>(tail, Bh, Bl, vnormb);

    dim3 grid(ns / 128, cs / 128, nc);
    score_kernel<<<grid, 256, 0, stream>>>(Ah, Al, Bh, Bl, vnormb, row_x2, row_c, row_sc,
                                           head_bias, tail_bias, (float*)d_out, cs, ns);
}

// Round 4
// 145.741 us; speedup vs baseline: 2.2380x; 1.0189x over previous
//
#include <hip/hip_runtime.h>
#include <math.h>

#define DEV static __device__ __forceinline__

constexpr float MIN_NORM = 1e-15f;
constexpr float BALL_EPS = 1e-5f;
constexpr int D = 512;          // feature dim (fixed by problem)

typedef float f32x4 __attribute__((ext_vector_type(4)));
typedef short short8v __attribute__((ext_vector_type(8)));
typedef unsigned short ushort8v __attribute__((ext_vector_type(8)));

DEV float wave_sum(float v) {
#pragma unroll
    for (int o = 32; o > 0; o >>= 1) v += __shfl_xor(v, o, 64);
    return v;
}

DEV float tanh_clip(float x) {
    x = fminf(fmaxf(x, -15.0f), 15.0f);
    return tanhf(x);
}

// bf16 split helpers (RNE)
DEV unsigned short f2bf(float f) {
    unsigned int u = __float_as_uint(f);
    u = (u + 0x7FFFu + ((u >> 16) & 1u)) >> 16;
    return (unsigned short)u;
}
DEV float bf2f(unsigned short h) { return __uint_as_float(((unsigned int)h) << 16); }

// ---------------------------------------------------------------------------
// Kernel A: per-row preprocessing (unchanged from round 3).
// ---------------------------------------------------------------------------
__global__ __launch_bounds__(64)
void preprocess_kernel(const float* __restrict__ head,
                       const float* __restrict__ rel,
                       const float* __restrict__ rel_diag,
                       const float* __restrict__ curvature,
                       const float* __restrict__ context,
                       const float* __restrict__ scale_p,
                       unsigned short* __restrict__ Ah,
                       unsigned short* __restrict__ Al,
                       float* __restrict__ row_x2,
                       float* __restrict__ row_c,
                       float* __restrict__ row_sc)
{
    const int row  = blockIdx.x;
    const int lane = threadIdx.x;
    const int base = lane * 8;
    const size_t roff = (size_t)row * D;
    const size_t doff = (size_t)row * 2 * D;

    float hv[8], rv[8], gv[8], fv[8], cxv[8];
    *(float4*)&hv[0]  = *(const float4*)(head + roff + base);
    *(float4*)&hv[4]  = *(const float4*)(head + roff + base + 4);
    *(float4*)&rv[0]  = *(const float4*)(rel + roff + base);
    *(float4*)&rv[4]  = *(const float4*)(rel + roff + base + 4);
    *(float4*)&gv[0]  = *(const float4*)(rel_diag + doff + base);
    *(float4*)&gv[4]  = *(const float4*)(rel_diag + doff + base + 4);
    *(float4*)&fv[0]  = *(const float4*)(rel_diag + doff + D + base);
    *(float4*)&fv[4]  = *(const float4*)(rel_diag + doff + D + base + 4);
    *(float4*)&cxv[0] = *(const float4*)(context + roff + base);
    *(float4*)&cxv[4] = *(const float4*)(context + roff + base + 4);

    float rq[8], rf[8];
#pragma unroll
    for (int p = 0; p < 4; ++p) {
        const float x0 = hv[2*p], x1 = hv[2*p+1];
        float g0 = gv[2*p], g1 = gv[2*p+1];
        const float gn = fmaxf(sqrtf(g0*g0 + g1*g1), MIN_NORM);
        g0 /= gn; g1 /= gn;
        rq[2*p]   = g0*x0 - g1*x1;       // rotation
        rq[2*p+1] = g0*x1 + g1*x0;
        float f0 = fv[2*p], f1 = fv[2*p+1];
        const float fn = fmaxf(sqrtf(f0*f0 + f1*f1), MIN_NORM);
        f0 /= fn; f1 /= fn;
        rf[2*p]   = f0*x0 + f1*x1;       // reflection
        rf[2*p+1] = f1*x0 - f0*x1;
    }

    float s0=0,s1=0,s2=0,s3=0,s4=0,s5=0,s6=0,s7=0;
#pragma unroll
    for (int e = 0; e < 8; ++e) {
        s0 += cxv[e]*rf[e];   s1 += cxv[e]*rq[e];
        s2 += rv[e]*rv[e];    s3 += rf[e]*rv[e];
        s4 += rq[e]*rv[e];    s5 += rf[e]*rf[e];
        s6 += rq[e]*rq[e];    s7 += rf[e]*rq[e];
    }
    s0 = wave_sum(s0); s1 = wave_sum(s1); s2 = wave_sum(s2); s3 = wave_sum(s3);
    s4 = wave_sum(s4); s5 = wave_sum(s5); s6 = wave_sum(s6); s7 = wave_sum(s7);

    const float cu = curvature[row];
    const float c  = fmaxf(cu, 0.0f) + log1pf(expf(-fabsf(cu)));
    const float sqc = sqrtf(c);
    const float sc  = scale_p[0];

    const float a0 = s0 * sc, a1 = s1 * sc;
    const float mx = fmaxf(a0, a1);
    const float e0 = expf(a0 - mx), e1 = expf(a1 - mx);
    const float w0 = e0 / (e0 + e1);
    const float w1 = 1.0f - w0;

    const float att2    = fmaxf(w0*w0*s5 + 2.0f*w0*w1*s7 + w1*w1*s6, 0.0f);
    const float attdrel = w0*s3 + w1*s4;
    const float u_att = fmaxf(sqrtf(att2), MIN_NORM);
    const float u_rel = fmaxf(sqrtf(s2), MIN_NORM);

    const float kl = tanh_clip(sqc * u_att) / (sqc * u_att);
    const float kr = tanh_clip(sqc * u_rel) / (sqc * u_rel);

    const float x2 = kl*kl*att2;
    const float y2 = kr*kr*s2;
    const float xy = kl*kr*attdrel;

    const float Am  = 1.0f + 2.0f*c*xy + c*y2;
    const float Bm  = 1.0f - c*x2;
    const float den = fmaxf(1.0f + 2.0f*c*xy + c*c*x2*y2, MIN_NORM);
    const float inv_den = 1.0f / den;

    float pre[8];
    float r2p = 0.0f;
#pragma unroll
    for (int e = 0; e < 8; ++e) {
        const float attq = w0*rf[e] + w1*rq[e];
        pre[e] = (Am*kl*attq + Bm*kr*rv[e]) * inv_den;
        r2p += pre[e]*pre[e];
    }
    r2p = wave_sum(r2p);

    const float nrm  = fmaxf(sqrtf(r2p), MIN_NORM);
    const float maxn = (1.0f - BALL_EPS) / sqc;
    const float psc  = (nrm > maxn) ? (maxn / nrm) : 1.0f;

    ushort8v hi, lo;
#pragma unroll
    for (int e = 0; e < 8; ++e) {
        const float o = pre[e] * psc;
        const unsigned short hb_ = f2bf(o);
        hi[e] = hb_;
        lo[e] = f2bf(o - bf2f(hb_));
    }
    *(ushort8v*)(Ah + roff + base) = hi;
    *(ushort8v*)(Al + roff + base) = lo;

    if (lane == 0) {
        row_x2[row] = r2p * psc * psc;
        row_c[row]  = c;
        row_sc[row] = sqc;
    }
}

// ---------------------------------------------------------------------------
// Kernel B: per-tail-row L2 norm + bf16 hi/lo split of tail (unchanged).
// ---------------------------------------------------------------------------
__global__ __launch_bounds__(64)
void tailprep_kernel(const float* __restrict__ tail,
                     unsigned short* __restrict__ Bh,
                     unsigned short* __restrict__ Bl,
                     float* __restrict__ vnorm)
{
    const int row  = blockIdx.x;
    const int lane = threadIdx.x;
    const size_t roff = (size_t)row * D + lane * 8;
    float v[8];
    *(float4*)&v[0] = *(const float4*)(tail + roff);
    *(float4*)&v[4] = *(const float4*)(tail + roff + 4);
    float s = 0.0f;
    ushort8v hi, lo;
#pragma unroll
    for (int e = 0; e < 8; ++e) {
        s += v[e]*v[e];
        const unsigned short hb_ = f2bf(v[e]);
        hi[e] = hb_;
        lo[e] = f2bf(v[e] - bf2f(hb_));
    }
    s = wave_sum(s);
    *(ushort8v*)(Bh + roff) = hi;
    *(ushort8v*)(Bl + roff) = lo;
    if (lane == 0) vnorm[row] = sqrtf(s);
}

// ---------------------------------------------------------------------------
// Kernel C: 256x256 tile, 8 waves (2x4, wave tile 128x64), BK=32 (hi|lo
// packed 128B rows), double-buffered 128KB LDS, 4-phase schedule per K-step:
//   phase p: [stage-issue next tile: A @p0, B @p1] ; ds_read A m=2p,2p+1
//            (+ all B frags @p0) ; s_barrier ; setprio(1) ; 24 MFMA ;
//            setprio(0) ; s_barrier
// One __syncthreads() per K-step drains staging that was issued 3-4 phases
// earlier (latency covered by MFMA work) -> T3+T4; setprio = T5; XOR
// involution both sides = T2 (0 conflicts measured).
// ---------------------------------------------------------------------------
__global__ __launch_bounds__(512, 2)
void score_kernel(const unsigned short* __restrict__ Ah,
                  const unsigned short* __restrict__ Al,
                  const unsigned short* __restrict__ Bh,
                  const unsigned short* __restrict__ Bl,
                  const float* __restrict__ vnorm,
                  const float* __restrict__ row_x2,
                  const float* __restrict__ row_c,
                  const float* __restrict__ row_sc,
                  const float* __restrict__ head_bias,
                  const float* __restrict__ tail_bias,
                  float* __restrict__ out,
                  int cs, int ns)
{
    extern __shared__ __align__(16) char smem[];   // 2 x (A 32KB | B 32KB)

    const int bz = blockIdx.z;
    const int m0 = blockIdx.y * 256;
    const int n0 = blockIdx.x * 256;
    const int tid  = threadIdx.x;
    const int lane = tid & 63;
    const int w    = tid >> 6;
    const int wr   = w >> 2, wn = w & 3;          // 2x4 wave grid, 128x64 each
    const int lrow = lane & 15, lg = lane >> 4;   // fragment row / k-group

    f32x4 acc[8][4];
#pragma unroll
    for (int i = 0; i < 8; ++i)
#pragma unroll
        for (int j = 0; j < 4; ++j) acc[i][j] = f32x4{0.f, 0.f, 0.f, 0.f};

    const size_t Aoff = (size_t)(bz * cs + m0) * D;
    const size_t Boff = (size_t)(bz * ns + n0) * D;

    // stage one 256x128B panel (hi|lo packed, source-side XOR involution)
#define STAGE_PANEL(dstbase, Hi, Lo, Goff, K0)                                     \
    do {                                                                           \
        _Pragma("unroll")                                                          \
        for (int it_ = 0; it_ < 4; ++it_) {                                        \
            const int L_ = it_ * 512 + tid;                                        \
            const int r_ = L_ >> 3, s_ = L_ & 7;                                   \
            const int kc_ = s_ ^ (r_ & 7);                                         \
            const unsigned short* src_ = (kc_ < 4)                                 \
                ? Hi + Goff + (size_t)r_ * D + (K0) + kc_ * 8                      \
                : Lo + Goff + (size_t)r_ * D + (K0) + (kc_ - 4) * 8;               \
            __builtin_amdgcn_global_load_lds(                                      \
                (const __attribute__((address_space(1))) unsigned int*)src_,       \
                (__attribute__((address_space(3))) unsigned int*)((dstbase) + L_ * 16), \
                16, 0, 0);                                                         \
        }                                                                          \
    } while (0)

#define READ_A(M, AH_, AL_)                                                        \
    do {                                                                           \
        const int r_ = wr * 128 + (M) * 16 + lrow;                                 \
        const char* rp_ = curb + r_ * 128;                                         \
        AH_ = *(const short8v*)(rp_ + ((lg    ) ^ (r_ & 7)) * 16);                 \
        AL_ = *(const short8v*)(rp_ + ((lg + 4) ^ (r_ & 7)) * 16);                 \
    } while (0)

#define MFMA_(A_, B_, C_) __builtin_amdgcn_mfma_f32_16x16x32_bf16(A_, B_, C_, 0, 0, 0)

    // tri-product for two m-fragments; product-major order -> dep distance 8
#define TRIPROD(M0, M1)                                                            \
    do {                                                                           \
        _Pragma("unroll") for (int n = 0; n < 4; ++n) acc[M0][n] = MFMA_(ah0, bh[n], acc[M0][n]); \
        _Pragma("unroll") for (int n = 0; n < 4; ++n) acc[M1][n] = MFMA_(ah1, bh[n], acc[M1][n]); \
        _Pragma("unroll") for (int n = 0; n < 4; ++n) acc[M0][n] = MFMA_(ah0, bl[n], acc[M0][n]); \
        _Pragma("unroll") for (int n = 0; n < 4; ++n) acc[M1][n] = MFMA_(ah1, bl[n], acc[M1][n]); \
        _Pragma("unroll") for (int n = 0; n < 4; ++n) acc[M0][n] = MFMA_(al0, bh[n], acc[M0][n]); \
        _Pragma("unroll") for (int n = 0; n < 4; ++n) acc[M1][n] = MFMA_(al1, bh[n], acc[M1][n]); \
    } while (0)

    // prologue: stage tile 0 into buffer 0
    STAGE_PANEL(smem, Ah, Al, Aoff, 0);
    STAGE_PANEL(smem + 32768, Bh, Bl, Boff, 0);
    __syncthreads();

#pragma unroll 1
    for (int t = 0; t < 16; ++t) {
        char* curb = smem + (t & 1) * 65536;
        char* nxtb = smem + ((t + 1) & 1) * 65536;
        const int k0n = (t + 1) * 32;
        const bool more = (t < 15);

        short8v bh[4], bl[4];
        short8v ah0, al0, ah1, al1;

        // ---- phase 0: stage A(next) ; read B frags + A m0,m1 ; 24 MFMA ----
        if (more) STAGE_PANEL(nxtb, Ah, Al, Aoff, k0n);
#pragma unroll
        for (int n = 0; n < 4; ++n) {
            const int r_ = wn * 64 + n * 16 + lrow;
            const char* rp_ = curb + 32768 + r_ * 128;
            bh[n] = *(const short8v*)(rp_ + ((lg    ) ^ (r_ & 7)) * 16);
            bl[n] = *(const short8v*)(rp_ + ((lg + 4) ^ (r_ & 7)) * 16);
        }
        READ_A(0, ah0, al0);
        READ_A(1, ah1, al1);
        __builtin_amdgcn_s_barrier();
        __builtin_amdgcn_s_setprio(1);
        TRIPROD(0, 1);
        __builtin_amdgcn_s_setprio(0);
        __builtin_amdgcn_s_barrier();

        // ---- phase 1: stage B(next) ; read A m2,m3 ; 24 MFMA ----
        if (more) STAGE_PANEL(nxtb + 32768, Bh, Bl, Boff, k0n);
        READ_A(2, ah0, al0);
        READ_A(3, ah1, al1);
        __builtin_amdgcn_s_barrier();
        __builtin_amdgcn_s_setprio(1);
        TRIPROD(2, 3);
        __builtin_amdgcn_s_setprio(0);
        __builtin_amdgcn_s_barrier();

        // ---- phase 2 ----
        READ_A(4, ah0, al0);
        READ_A(5, ah1, al1);
        __builtin_amdgcn_s_barrier();
        __builtin_amdgcn_s_setprio(1);
        TRIPROD(4, 5);
        __builtin_amdgcn_s_setprio(0);
        __builtin_amdgcn_s_barrier();

        // ---- phase 3 ----
        READ_A(6, ah0, al0);
        READ_A(7, ah1, al1);
        __builtin_amdgcn_s_barrier();
        __builtin_amdgcn_s_setprio(1);
        TRIPROD(6, 7);
        __builtin_amdgcn_s_setprio(0);

        // drain staging (issued 3-4 phases ago) + flip buffers
        __syncthreads();
    }

    // ---- fused hyperbolic-distance epilogue ----
    // C/D layout (m89-verified): col = lane&15, row = (lane>>4)*4 + q
    const int nbase = n0 + wn * 64 + lrow;
    float rvn[4], vnv[4], tb[4];
#pragma unroll
    for (int j = 0; j < 4; ++j) {
        const int gn = bz * ns + nbase + j * 16;
        const float vn = vnorm[gn];
        vnv[j] = vn;
        rvn[j] = 1.0f / vn;
        tb[j]  = tail_bias[gn];
    }
#pragma unroll
    for (int i = 0; i < 8; ++i) {
#pragma unroll
        for (int q = 0; q < 4; ++q) {
            const int gm = bz * cs + m0 + wr * 128 + i * 16 + lg * 4 + q;
            const float x2  = row_x2[gm];
            const float cc  = row_c[gm];
            const float scq = row_sc[gm];
            const float hb  = head_bias[gm];
            const float rscq = 1.0f / scq;
            float* orow = out + (size_t)gm * ns + nbase;
#pragma unroll
            for (int j = 0; j < 4; ++j) {
                const float xv = acc[i][j][q] * rvn[j];
                float xx = fminf(scq * vnv[j], 15.0f);           // x >= 0 always
                const float ey = __expf(2.0f * xx);
                const float g  = (1.0f - 2.0f / (ey + 1.0f)) * rscq;  // tanh/sqc
                const float c1 = 1.0f - 2.0f*cc*g*xv + cc*g*g;
                const float c2 = 1.0f - cc*x2;
                const float num = sqrtf(fmaxf(c1*c1*x2 + c2*c2*g*g - 2.0f*c1*c2*g*xv, 0.0f));
                const float den = fmaxf(1.0f - 2.0f*cc*g*xv + cc*cc*g*g*x2, MIN_NORM);
                float t = scq * num * __builtin_amdgcn_rcpf(den);
                t = fminf(t, 1.0f - 1e-5f);                      // t >= 0 always
                const float ath = 0.5f * __logf((1.0f + t) * __builtin_amdgcn_rcpf(1.0f - t));
                const float dist = 2.0f * rscq * ath;
                orow[j * 16] = -dist * dist + hb + tb[j];
            }
        }
    }
#undef STAGE_PANEL
#undef READ_A
#undef MFMA_
#undef TRIPROD
}

// ---------------------------------------------------------------------------
extern "C" void kernel_launch(void* const* d_in, const int* in_sizes, int n_in,
                              void* d_out, int out_size, void* d_ws, size_t ws_size,
                              hipStream_t stream)
{
    const float* head      = (const float*)d_in[0];
    const float* head_bias = (const float*)d_in[1];
    const float* rel       = (const float*)d_in[2];
    const float* rel_diag  = (const float*)d_in[3];
    const float* curvature = (const float*)d_in[4];
    const float* context   = (const float*)d_in[5];
    const float* scale     = (const float*)d_in[6];
    const float* tail      = (const float*)d_in[7];
    const float* tail_bias = (const float*)d_in[8];

    const int B  = in_sizes[1];        // 16384
    const int T  = in_sizes[8];        // 16384
    const int ns = out_size / B;       // 1024
    const int nc = T / ns;             // 16
    const int cs = B / nc;             // 1024

    // ws layout: Ah | Al | Bh | Bl (bf16) then f32 scalars
    unsigned short* Ah = (unsigned short*)d_ws;
    unsigned short* Al = Ah + (size_t)B * D;
    unsigned short* Bh = Al + (size_t)B * D;
    unsigned short* Bl = Bh + (size_t)T * D;
    float* row_x2 = (float*)(Bl + (size_t)T * D);
    float* row_c  = row_x2 + B;
    float* row_sc = row_c + B;
    float* vnormb = row_sc + B;

    preprocess_kernel<<<B, 64, 0, stream>>>(head, rel, rel_diag, curvature, context,
                                            scale, Ah, Al, row_x2, row_c, row_sc);
    tailprep_kernel<<<T, 64, 0, stream>>>(tail, Bh, Bl, vnormb);

    (void)hipFuncSetAttribute((const void*)score_kernel,
                              hipFuncAttributeMaxDynamicSharedMemorySize, 131072);
    dim3 grid(ns / 256, cs / 256, nc);
    score_kernel<<<grid, 512, 131072, stream>>>(Ah, Al, Bh, Bl, vnormb, row_x2, row_c,
                                                row_sc, head_bias, tail_bias,
                                                (float*)d_out, cs, ns);
}

// Round 5
// 136.773 us; speedup vs baseline: 2.3847x; 1.0656x over previous
//
#include <hip/hip_runtime.h>
#include <math.h>

#define DEV static __device__ __forceinline__

constexpr float MIN_NORM = 1e-15f;
constexpr float BALL_EPS = 1e-5f;
constexpr int D = 512;          // feature dim (fixed by problem)

typedef float f32x4 __attribute__((ext_vector_type(4)));
typedef short short8v __attribute__((ext_vector_type(8)));
typedef unsigned short ushort8v __attribute__((ext_vector_type(8)));

DEV float wave_sum(float v) {
#pragma unroll
    for (int o = 32; o > 0; o >>= 1) v += __shfl_xor(v, o, 64);
    return v;
}

DEV float tanh_clip(float x) {
    x = fminf(fmaxf(x, -15.0f), 15.0f);
    return tanhf(x);
}

// bf16 split helpers (RNE)
DEV unsigned short f2bf(float f) {
    unsigned int u = __float_as_uint(f);
    u = (u + 0x7FFFu + ((u >> 16) & 1u)) >> 16;
    return (unsigned short)u;
}
DEV float bf2f(unsigned short h) { return __uint_as_float(((unsigned int)h) << 16); }

// Packed panel layout (the exact LDS image, so staging is a linear copy):
//   pack[kb][row][slot], kb = K-tile (32 K-elems), slot = 16B chunk 0..7.
//   Logical chunks: 0-3 = hi k-sub 0..3, 4-7 = lo k-sub 0..3.
//   Stored at slot = chunk ^ (row & 7)  (XOR involution, T2 both-sides).
// Lane l of a 64-lane prep wave holds elems [l*8, l*8+8): kb = l>>2, chunk = l&3.
DEV void write_packed_row(unsigned short* pack, size_t nrow, int row,
                          int lane, ushort8v hi, ushort8v lo)
{
    const int kb  = lane >> 2;
    const int cch = lane & 3;
    const int rx  = row & 7;
    unsigned short* dst = pack + ((size_t)kb * nrow + row) * 64;   // 128B rows
    *(ushort8v*)(dst + ((cch ^ rx) * 8))       = hi;
    *(ushort8v*)(dst + (((cch + 4) ^ rx) * 8)) = lo;
}

// ---------------------------------------------------------------------------
// Kernel A: per-row preprocessing. One wave per row, 8 elems/lane.
// Emits res as packed hi/lo bf16 panel + per-row scalars.
// ---------------------------------------------------------------------------
__global__ __launch_bounds__(64)
void preprocess_kernel(const float* __restrict__ head,
                       const float* __restrict__ rel,
                       const float* __restrict__ rel_diag,
                       const float* __restrict__ curvature,
                       const float* __restrict__ context,
                       const float* __restrict__ scale_p,
                       unsigned short* __restrict__ packA,
                       float* __restrict__ row_x2,
                       float* __restrict__ row_c,
                       float* __restrict__ row_sc,
                       int nrow)
{
    const int row  = blockIdx.x;
    const int lane = threadIdx.x;
    const int base = lane * 8;
    const size_t roff = (size_t)row * D;
    const size_t doff = (size_t)row * 2 * D;

    float hv[8], rv[8], gv[8], fv[8], cxv[8];
    *(float4*)&hv[0]  = *(const float4*)(head + roff + base);
    *(float4*)&hv[4]  = *(const float4*)(head + roff + base + 4);
    *(float4*)&rv[0]  = *(const float4*)(rel + roff + base);
    *(float4*)&rv[4]  = *(const float4*)(rel + roff + base + 4);
    *(float4*)&gv[0]  = *(const float4*)(rel_diag + doff + base);
    *(float4*)&gv[4]  = *(const float4*)(rel_diag + doff + base + 4);
    *(float4*)&fv[0]  = *(const float4*)(rel_diag + doff + D + base);
    *(float4*)&fv[4]  = *(const float4*)(rel_diag + doff + D + base + 4);
    *(float4*)&cxv[0] = *(const float4*)(context + roff + base);
    *(float4*)&cxv[4] = *(const float4*)(context + roff + base + 4);

    float rq[8], rf[8];
#pragma unroll
    for (int p = 0; p < 4; ++p) {
        const float x0 = hv[2*p], x1 = hv[2*p+1];
        float g0 = gv[2*p], g1 = gv[2*p+1];
        const float gn = fmaxf(sqrtf(g0*g0 + g1*g1), MIN_NORM);
        g0 /= gn; g1 /= gn;
        rq[2*p]   = g0*x0 - g1*x1;       // rotation
        rq[2*p+1] = g0*x1 + g1*x0;
        float f0 = fv[2*p], f1 = fv[2*p+1];
        const float fn = fmaxf(sqrtf(f0*f0 + f1*f1), MIN_NORM);
        f0 /= fn; f1 /= fn;
        rf[2*p]   = f0*x0 + f1*x1;       // reflection
        rf[2*p+1] = f1*x0 - f0*x1;
    }

    float s0=0,s1=0,s2=0,s3=0,s4=0,s5=0,s6=0,s7=0;
#pragma unroll
    for (int e = 0; e < 8; ++e) {
        s0 += cxv[e]*rf[e];   s1 += cxv[e]*rq[e];
        s2 += rv[e]*rv[e];    s3 += rf[e]*rv[e];
        s4 += rq[e]*rv[e];    s5 += rf[e]*rf[e];
        s6 += rq[e]*rq[e];    s7 += rf[e]*rq[e];
    }
    s0 = wave_sum(s0); s1 = wave_sum(s1); s2 = wave_sum(s2); s3 = wave_sum(s3);
    s4 = wave_sum(s4); s5 = wave_sum(s5); s6 = wave_sum(s6); s7 = wave_sum(s7);

    const float cu = curvature[row];
    const float c  = fmaxf(cu, 0.0f) + log1pf(expf(-fabsf(cu)));
    const float sqc = sqrtf(c);
    const float sc  = scale_p[0];

    const float a0 = s0 * sc, a1 = s1 * sc;
    const float mx = fmaxf(a0, a1);
    const float e0 = expf(a0 - mx), e1 = expf(a1 - mx);
    const float w0 = e0 / (e0 + e1);
    const float w1 = 1.0f - w0;

    const float att2    = fmaxf(w0*w0*s5 + 2.0f*w0*w1*s7 + w1*w1*s6, 0.0f);
    const float attdrel = w0*s3 + w1*s4;
    const float u_att = fmaxf(sqrtf(att2), MIN_NORM);
    const float u_rel = fmaxf(sqrtf(s2), MIN_NORM);

    const float kl = tanh_clip(sqc * u_att) / (sqc * u_att);
    const float kr = tanh_clip(sqc * u_rel) / (sqc * u_rel);

    const float x2 = kl*kl*att2;
    const float y2 = kr*kr*s2;
    const float xy = kl*kr*attdrel;

    const float Am  = 1.0f + 2.0f*c*xy + c*y2;
    const float Bm  = 1.0f - c*x2;
    const float den = fmaxf(1.0f + 2.0f*c*xy + c*c*x2*y2, MIN_NORM);
    const float inv_den = 1.0f / den;

    float pre[8];
    float r2p = 0.0f;
#pragma unroll
    for (int e = 0; e < 8; ++e) {
        const float attq = w0*rf[e] + w1*rq[e];
        pre[e] = (Am*kl*attq + Bm*kr*rv[e]) * inv_den;
        r2p += pre[e]*pre[e];
    }
    r2p = wave_sum(r2p);

    const float nrm  = fmaxf(sqrtf(r2p), MIN_NORM);
    const float maxn = (1.0f - BALL_EPS) / sqc;
    const float psc  = (nrm > maxn) ? (maxn / nrm) : 1.0f;

    ushort8v hi, lo;
#pragma unroll
    for (int e = 0; e < 8; ++e) {
        const float o = pre[e] * psc;
        const unsigned short hb_ = f2bf(o);
        hi[e] = hb_;
        lo[e] = f2bf(o - bf2f(hb_));
    }
    write_packed_row(packA, (size_t)nrow, row, lane, hi, lo);

    if (lane == 0) {
        row_x2[row] = r2p * psc * psc;
        row_c[row]  = c;
        row_sc[row] = sqc;
    }
}

// ---------------------------------------------------------------------------
// Kernel B: per-tail-row L2 norm + packed hi/lo bf16 panel of tail.
// ---------------------------------------------------------------------------
__global__ __launch_bounds__(64)
void tailprep_kernel(const float* __restrict__ tail,
                     unsigned short* __restrict__ packB,
                     float* __restrict__ vnorm,
                     int nrow)
{
    const int row  = blockIdx.x;
    const int lane = threadIdx.x;
    const size_t roff = (size_t)row * D + lane * 8;
    float v[8];
    *(float4*)&v[0] = *(const float4*)(tail + roff);
    *(float4*)&v[4] = *(const float4*)(tail + roff + 4);
    float s = 0.0f;
    ushort8v hi, lo;
#pragma unroll
    for (int e = 0; e < 8; ++e) {
        s += v[e]*v[e];
        const unsigned short hb_ = f2bf(v[e]);
        hi[e] = hb_;
        lo[e] = f2bf(v[e] - bf2f(hb_));
    }
    s = wave_sum(s);
    write_packed_row(packB, (size_t)nrow, row, lane, hi, lo);
    if (lane == 0) vnorm[row] = sqrtf(s);
}

// ---------------------------------------------------------------------------
// Kernel C: 256x256 tile, 8 waves (2x4, wave tile 128x64), BK=32 (hi|lo
// packed 128B rows), double-buffered 128KB LDS, 4-phase schedule per K-step.
// Staging is a LINEAR copy of one 16KB half-panel per phase (B-top, B-bot,
// A-top, A-bot) from the pre-packed pre-swizzled global panels -> smooth
// 2 loads/thread/phase, trivial addressing. End-of-step __syncthreads drains
// staging whose youngest load has >=1 MFMA phase of latency cover.
// XCD swizzle: each XCD owns 2 whole batches (panel reuse in own L2).
// ---------------------------------------------------------------------------
__global__ __launch_bounds__(512, 2)
void score_kernel(const unsigned short* __restrict__ packA,
                  const unsigned short* __restrict__ packB,
                  const float* __restrict__ vnorm,
                  const float* __restrict__ row_x2,
                  const float* __restrict__ row_c,
                  const float* __restrict__ row_sc,
                  const float* __restrict__ head_bias,
                  const float* __restrict__ tail_bias,
                  float* __restrict__ out,
                  int cs, int ns, int nrowA, int nrowB)
{
    extern __shared__ __align__(16) char smem[];   // 2 x (A 32KB | B 32KB)

    // XCD-aware remap: orig%8 = XCD; give each XCD a contiguous 32-block
    // chunk (= 2 whole batches). Bijective for 256 blocks.
    const int orig = blockIdx.x;
    const int wg = (orig & 7) * 32 + (orig >> 3);
    const int bz = wg >> 4;
    const int by = (wg >> 2) & 3;
    const int bx = wg & 3;
    const int m0 = by * 256;
    const int n0 = bx * 256;

    const int tid  = threadIdx.x;
    const int lane = tid & 63;
    const int w    = tid >> 6;
    const int wr   = w >> 2, wn = w & 3;          // 2x4 wave grid, 128x64 each
    const int lrow = lane & 15, lg = lane >> 4;   // fragment row / k-group

    f32x4 acc[8][4];
#pragma unroll
    for (int i = 0; i < 8; ++i)
#pragma unroll
        for (int j = 0; j < 4; ++j) acc[i][j] = f32x4{0.f, 0.f, 0.f, 0.f};

    // per-K-tile packed panel bases (each panel tile: 256 rows x 128B = 32KB)
    const char* srcA0 = (const char*)packA + (size_t)(bz * cs + m0) * 128;
    const char* srcB0 = (const char*)packB + (size_t)(bz * ns + n0) * 128;
    const size_t strideA = (size_t)nrowA * 128;   // per-kb stride
    const size_t strideB = (size_t)nrowB * 128;

    // linear copy of one 16KB half-panel (2 x 16B per thread)
#define STAGE_HALF(dst, src, half)                                                 \
    do {                                                                           \
        const int bo_ = (half) * 16384 + tid * 16;                                 \
        __builtin_amdgcn_global_load_lds(                                          \
            (const __attribute__((address_space(1))) unsigned int*)((src) + bo_),  \
            (__attribute__((address_space(3))) unsigned int*)((dst) + bo_),        \
            16, 0, 0);                                                             \
        __builtin_amdgcn_global_load_lds(                                          \
            (const __attribute__((address_space(1))) unsigned int*)((src) + bo_ + 8192), \
            (__attribute__((address_space(3))) unsigned int*)((dst) + bo_ + 8192), \
            16, 0, 0);                                                             \
    } while (0)

#define READ_A(M, AH_, AL_)                                                        \
    do {                                                                           \
        const int r_ = wr * 128 + (M) * 16 + lrow;                                 \
        const char* rp_ = curb + r_ * 128;                                         \
        AH_ = *(const short8v*)(rp_ + ((lg    ) ^ (r_ & 7)) * 16);                 \
        AL_ = *(const short8v*)(rp_ + ((lg + 4) ^ (r_ & 7)) * 16);                 \
    } while (0)

#define MFMA_(A_, B_, C_) __builtin_amdgcn_mfma_f32_16x16x32_bf16(A_, B_, C_, 0, 0, 0)

    // tri-product for two m-fragments; product-major order -> dep distance 8
#define TRIPROD(M0, M1)                                                            \
    do {                                                                           \
        _Pragma("unroll") for (int n = 0; n < 4; ++n) acc[M0][n] = MFMA_(ah0, bh[n], acc[M0][n]); \
        _Pragma("unroll") for (int n = 0; n < 4; ++n) acc[M1][n] = MFMA_(ah1, bh[n], acc[M1][n]); \
        _Pragma("unroll") for (int n = 0; n < 4; ++n) acc[M0][n] = MFMA_(ah0, bl[n], acc[M0][n]); \
        _Pragma("unroll") for (int n = 0; n < 4; ++n) acc[M1][n] = MFMA_(ah1, bl[n], acc[M1][n]); \
        _Pragma("unroll") for (int n = 0; n < 4; ++n) acc[M0][n] = MFMA_(al0, bh[n], acc[M0][n]); \
        _Pragma("unroll") for (int n = 0; n < 4; ++n) acc[M1][n] = MFMA_(al1, bh[n], acc[M1][n]); \
    } while (0)

    // prologue: stage tile 0 into buffer 0
    STAGE_HALF(smem,         srcA0, 0);
    STAGE_HALF(smem,         srcA0, 1);
    STAGE_HALF(smem + 32768, srcB0, 0);
    STAGE_HALF(smem + 32768, srcB0, 1);
    __syncthreads();

#pragma unroll 1
    for (int t = 0; t < 16; ++t) {
        char* curb = smem + (t & 1) * 65536;
        char* nxtb = smem + ((t + 1) & 1) * 65536;
        const char* srcA_n = srcA0 + (size_t)(t + 1) * strideA;
        const char* srcB_n = srcB0 + (size_t)(t + 1) * strideB;
        const bool more = (t < 15);

        short8v bh[4], bl[4];
        short8v ah0, al0, ah1, al1;

        // ---- phase 0: stage B-top(next) ; read B frags + A m0,m1 ----
        if (more) STAGE_HALF(nxtb + 32768, srcB_n, 0);
#pragma unroll
        for (int n = 0; n < 4; ++n) {
            const int r_ = wn * 64 + n * 16 + lrow;
            const char* rp_ = curb + 32768 + r_ * 128;
            bh[n] = *(const short8v*)(rp_ + ((lg    ) ^ (r_ & 7)) * 16);
            bl[n] = *(const short8v*)(rp_ + ((lg + 4) ^ (r_ & 7)) * 16);
        }
        READ_A(0, ah0, al0);
        READ_A(1, ah1, al1);
        __builtin_amdgcn_s_barrier();
        __builtin_amdgcn_s_setprio(1);
        TRIPROD(0, 1);
        __builtin_amdgcn_s_setprio(0);
        __builtin_amdgcn_s_barrier();

        // ---- phase 1: stage B-bot(next) ; read A m2,m3 ----
        if (more) STAGE_HALF(nxtb + 32768, srcB_n, 1);
        READ_A(2, ah0, al0);
        READ_A(3, ah1, al1);
        __builtin_amdgcn_s_barrier();
        __builtin_amdgcn_s_setprio(1);
        TRIPROD(2, 3);
        __builtin_amdgcn_s_setprio(0);
        __builtin_amdgcn_s_barrier();

        // ---- phase 2: stage A-top(next) ; read A m4,m5 ----
        if (more) STAGE_HALF(nxtb, srcA_n, 0);
        READ_A(4, ah0, al0);
        READ_A(5, ah1, al1);
        __builtin_amdgcn_s_barrier();
        __builtin_amdgcn_s_setprio(1);
        TRIPROD(4, 5);
        __builtin_amdgcn_s_setprio(0);
        __builtin_amdgcn_s_barrier();

        // ---- phase 3: stage A-bot(next) ; read A m6,m7 ----
        if (more) STAGE_HALF(nxtb, srcA_n, 1);
        READ_A(6, ah0, al0);
        READ_A(7, ah1, al1);
        __builtin_amdgcn_s_barrier();
        __builtin_amdgcn_s_setprio(1);
        TRIPROD(6, 7);
        __builtin_amdgcn_s_setprio(0);

        // drain staging (youngest load has >=1 phase of cover) + flip buffers
        __syncthreads();
    }

    // ---- fused hyperbolic-distance epilogue ----
    // C/D layout (m89-verified): col = lane&15, row = (lane>>4)*4 + q
    const int nbase = n0 + wn * 64 + lrow;
    float rvn[4], vnv[4], tb[4];
#pragma unroll
    for (int j = 0; j < 4; ++j) {
        const int gn = bz * ns + nbase + j * 16;
        const float vn = vnorm[gn];
        vnv[j] = vn;
        rvn[j] = 1.0f / vn;
        tb[j]  = tail_bias[gn];
    }
#pragma unroll
    for (int i = 0; i < 8; ++i) {
#pragma unroll
        for (int q = 0; q < 4; ++q) {
            const int gm = bz * cs + m0 + wr * 128 + i * 16 + lg * 4 + q;
            const float x2  = row_x2[gm];
            const float cc  = row_c[gm];
            const float scq = row_sc[gm];
            const float hb  = head_bias[gm];
            const float rscq = 1.0f / scq;
            float* orow = out + (size_t)gm * ns + nbase;
#pragma unroll
            for (int j = 0; j < 4; ++j) {
                const float xv = acc[i][j][q] * rvn[j];
                float xx = fminf(scq * vnv[j], 15.0f);           // x >= 0 always
                const float ey = __expf(2.0f * xx);
                const float g  = (1.0f - 2.0f / (ey + 1.0f)) * rscq;  // tanh/sqc
                const float c1 = 1.0f - 2.0f*cc*g*xv + cc*g*g;
                const float c2 = 1.0f - cc*x2;
                const float num = sqrtf(fmaxf(c1*c1*x2 + c2*c2*g*g - 2.0f*c1*c2*g*xv, 0.0f));
                const float den = fmaxf(1.0f - 2.0f*cc*g*xv + cc*cc*g*g*x2, MIN_NORM);
                float t = scq * num * __builtin_amdgcn_rcpf(den);
                t = fminf(t, 1.0f - 1e-5f);                      // t >= 0 always
                const float ath = 0.5f * __logf((1.0f + t) * __builtin_amdgcn_rcpf(1.0f - t));
                const float dist = 2.0f * rscq * ath;
                orow[j * 16] = -dist * dist + hb + tb[j];
            }
        }
    }
#undef STAGE_HALF
#undef READ_A
#undef MFMA_
#undef TRIPROD
}

// ---------------------------------------------------------------------------
extern "C" void kernel_launch(void* const* d_in, const int* in_sizes, int n_in,
                              void* d_out, int out_size, void* d_ws, size_t ws_size,
                              hipStream_t stream)
{
    const float* head      = (const float*)d_in[0];
    const float* head_bias = (const float*)d_in[1];
    const float* rel       = (const float*)d_in[2];
    const float* rel_diag  = (const float*)d_in[3];
    const float* curvature = (const float*)d_in[4];
    const float* context   = (const float*)d_in[5];
    const float* scale     = (const float*)d_in[6];
    const float* tail      = (const float*)d_in[7];
    const float* tail_bias = (const float*)d_in[8];

    const int B  = in_sizes[1];        // 16384
    const int T  = in_sizes[8];        // 16384
    const int ns = out_size / B;       // 1024
    const int nc = T / ns;             // 16
    const int cs = B / nc;             // 1024

    // ws layout: packA (16*B*64 ushorts = 32MB) | packB (32MB) | f32 scalars
    unsigned short* packA = (unsigned short*)d_ws;
    unsigned short* packB = packA + (size_t)16 * B * 64;
    float* row_x2 = (float*)(packB + (size_t)16 * T * 64);
    float* row_c  = row_x2 + B;
    float* row_sc = row_c + B;
    float* vnormb = row_sc + B;

    preprocess_kernel<<<B, 64, 0, stream>>>(head, rel, rel_diag, curvature, context,
                                            scale, packA, row_x2, row_c, row_sc, B);
    tailprep_kernel<<<T, 64, 0, stream>>>(tail, packB, vnormb, T);

    (void)hipFuncSetAttribute((const void*)score_kernel,
                              hipFuncAttributeMaxDynamicSharedMemorySize, 131072);
    const int nblk = (ns / 256) * (cs / 256) * nc;   // 256
    score_kernel<<<nblk, 512, 131072, stream>>>(packA, packB, vnormb, row_x2, row_c,
                                                row_sc, head_bias, tail_bias,
                                                (float*)d_out, cs, ns, B, T);
}

// Round 6
// 135.113 us; speedup vs baseline: 2.4140x; 1.0123x over previous
//
#include <hip/hip_runtime.h>
#include <math.h>

#define DEV static __device__ __forceinline__

constexpr float MIN_NORM = 1e-15f;
constexpr float BALL_EPS = 1e-5f;
constexpr int D = 512;          // feature dim (fixed by problem)

typedef float f32x4 __attribute__((ext_vector_type(4)));
typedef short short8v __attribute__((ext_vector_type(8)));
typedef unsigned short ushort8v __attribute__((ext_vector_type(8)));

DEV float wave_sum(float v) {
#pragma unroll
    for (int o = 32; o > 0; o >>= 1) v += __shfl_xor(v, o, 64);
    return v;
}

DEV float tanh_clip(float x) {
    x = fminf(fmaxf(x, -15.0f), 15.0f);
    return tanhf(x);
}

// bf16 split helpers (RNE)
DEV unsigned short f2bf(float f) {
    unsigned int u = __float_as_uint(f);
    u = (u + 0x7FFFu + ((u >> 16) & 1u)) >> 16;
    return (unsigned short)u;
}
DEV float bf2f(unsigned short h) { return __uint_as_float(((unsigned int)h) << 16); }

// Packed panel layout (exact LDS image; staging is a linear copy):
//   pack[kb][row][slot], kb = K-tile (32 K-elems), slot = 16B chunk 0..7.
//   chunks 0-3 = hi k-sub 0..3, 4-7 = lo. Stored slot = chunk ^ (row & 7).
DEV void write_packed_row(unsigned short* pack, size_t nrow, int row,
                          int lane, ushort8v hi, ushort8v lo)
{
    const int kb  = lane >> 2;
    const int cch = lane & 3;
    const int rx  = row & 7;
    unsigned short* dst = pack + ((size_t)kb * nrow + row) * 64;   // 128B rows
    *(ushort8v*)(dst + ((cch ^ rx) * 8))       = hi;
    *(ushort8v*)(dst + (((cch + 4) ^ rx) * 8)) = lo;
}

// ---------------------------------------------------------------------------
// Merged prep kernel: blocks [0,B) do head-row preprocessing, [B,B+T) do
// tail-row norm+split. One wave per row, 8 elems/lane.
// ---------------------------------------------------------------------------
__global__ __launch_bounds__(64)
void prep_kernel(const float* __restrict__ head,
                 const float* __restrict__ rel,
                 const float* __restrict__ rel_diag,
                 const float* __restrict__ curvature,
                 const float* __restrict__ context,
                 const float* __restrict__ scale_p,
                 const float* __restrict__ tail,
                 unsigned short* __restrict__ packA,
                 unsigned short* __restrict__ packB,
                 float* __restrict__ row_x2,
                 float* __restrict__ row_c,
                 float* __restrict__ row_sc,
                 float* __restrict__ vnorm,
                 int B, int T)
{
    const int lane = threadIdx.x;
    const int base = lane * 8;

    if ((int)blockIdx.x >= B) {
        // ---- tail path ----
        const int row = blockIdx.x - B;
        const size_t roff = (size_t)row * D + base;
        float v[8];
        *(float4*)&v[0] = *(const float4*)(tail + roff);
        *(float4*)&v[4] = *(const float4*)(tail + roff + 4);
        float s = 0.0f;
        ushort8v hi, lo;
#pragma unroll
        for (int e = 0; e < 8; ++e) {
            s += v[e]*v[e];
            const unsigned short hb_ = f2bf(v[e]);
            hi[e] = hb_;
            lo[e] = f2bf(v[e] - bf2f(hb_));
        }
        s = wave_sum(s);
        write_packed_row(packB, (size_t)T, row, lane, hi, lo);
        if (lane == 0) vnorm[row] = sqrtf(s);
        return;
    }

    // ---- head path ----
    const int row = blockIdx.x;
    const size_t roff = (size_t)row * D;
    const size_t doff = (size_t)row * 2 * D;

    float hv[8], rv[8], gv[8], fv[8], cxv[8];
    *(float4*)&hv[0]  = *(const float4*)(head + roff + base);
    *(float4*)&hv[4]  = *(const float4*)(head + roff + base + 4);
    *(float4*)&rv[0]  = *(const float4*)(rel + roff + base);
    *(float4*)&rv[4]  = *(const float4*)(rel + roff + base + 4);
    *(float4*)&gv[0]  = *(const float4*)(rel_diag + doff + base);
    *(float4*)&gv[4]  = *(const float4*)(rel_diag + doff + base + 4);
    *(float4*)&fv[0]  = *(const float4*)(rel_diag + doff + D + base);
    *(float4*)&fv[4]  = *(const float4*)(rel_diag + doff + D + base + 4);
    *(float4*)&cxv[0] = *(const float4*)(context + roff + base);
    *(float4*)&cxv[4] = *(const float4*)(context + roff + base + 4);

    float rq[8], rf[8];
#pragma unroll
    for (int p = 0; p < 4; ++p) {
        const float x0 = hv[2*p], x1 = hv[2*p+1];
        float g0 = gv[2*p], g1 = gv[2*p+1];
        const float gn = fmaxf(sqrtf(g0*g0 + g1*g1), MIN_NORM);
        g0 /= gn; g1 /= gn;
        rq[2*p]   = g0*x0 - g1*x1;       // rotation
        rq[2*p+1] = g0*x1 + g1*x0;
        float f0 = fv[2*p], f1 = fv[2*p+1];
        const float fn = fmaxf(sqrtf(f0*f0 + f1*f1), MIN_NORM);
        f0 /= fn; f1 /= fn;
        rf[2*p]   = f0*x0 + f1*x1;       // reflection
        rf[2*p+1] = f1*x0 - f0*x1;
    }

    float s0=0,s1=0,s2=0,s3=0,s4=0,s5=0,s6=0,s7=0;
#pragma unroll
    for (int e = 0; e < 8; ++e) {
        s0 += cxv[e]*rf[e];   s1 += cxv[e]*rq[e];
        s2 += rv[e]*rv[e];    s3 += rf[e]*rv[e];
        s4 += rq[e]*rv[e];    s5 += rf[e]*rf[e];
        s6 += rq[e]*rq[e];    s7 += rf[e]*rq[e];
    }
    s0 = wave_sum(s0); s1 = wave_sum(s1); s2 = wave_sum(s2); s3 = wave_sum(s3);
    s4 = wave_sum(s4); s5 = wave_sum(s5); s6 = wave_sum(s6); s7 = wave_sum(s7);

    const float cu = curvature[row];
    const float c  = fmaxf(cu, 0.0f) + log1pf(expf(-fabsf(cu)));
    const float sqc = sqrtf(c);
    const float sc  = scale_p[0];

    const float a0 = s0 * sc, a1 = s1 * sc;
    const float mx = fmaxf(a0, a1);
    const float e0 = expf(a0 - mx), e1 = expf(a1 - mx);
    const float w0 = e0 / (e0 + e1);
    const float w1 = 1.0f - w0;

    const float att2    = fmaxf(w0*w0*s5 + 2.0f*w0*w1*s7 + w1*w1*s6, 0.0f);
    const float attdrel = w0*s3 + w1*s4;
    const float u_att = fmaxf(sqrtf(att2), MIN_NORM);
    const float u_rel = fmaxf(sqrtf(s2), MIN_NORM);

    const float kl = tanh_clip(sqc * u_att) / (sqc * u_att);
    const float kr = tanh_clip(sqc * u_rel) / (sqc * u_rel);

    const float x2 = kl*kl*att2;
    const float y2 = kr*kr*s2;
    const float xy = kl*kr*attdrel;

    const float Am  = 1.0f + 2.0f*c*xy + c*y2;
    const float Bm  = 1.0f - c*x2;
    const float den = fmaxf(1.0f + 2.0f*c*xy + c*c*x2*y2, MIN_NORM);
    const float inv_den = 1.0f / den;

    float pre[8];
    float r2p = 0.0f;
#pragma unroll
    for (int e = 0; e < 8; ++e) {
        const float attq = w0*rf[e] + w1*rq[e];
        pre[e] = (Am*kl*attq + Bm*kr*rv[e]) * inv_den;
        r2p += pre[e]*pre[e];
    }
    r2p = wave_sum(r2p);

    const float nrm  = fmaxf(sqrtf(r2p), MIN_NORM);
    const float maxn = (1.0f - BALL_EPS) / sqc;
    const float psc  = (nrm > maxn) ? (maxn / nrm) : 1.0f;

    ushort8v hi, lo;
#pragma unroll
    for (int e = 0; e < 8; ++e) {
        const float o = pre[e] * psc;
        const unsigned short hb_ = f2bf(o);
        hi[e] = hb_;
        lo[e] = f2bf(o - bf2f(hb_));
    }
    write_packed_row(packA, (size_t)B, row, lane, hi, lo);

    if (lane == 0) {
        row_x2[row] = r2p * psc * psc;
        row_c[row]  = c;
        row_sc[row] = sqc;
    }
}

// ---------------------------------------------------------------------------
// Kernel C: 256x256 tile, 8 waves (2x4, wave tile 128x64), BK=32 hi|lo
// packed 128B rows, dbuf 128KB, C-QUADRANT 4-phase schedule with COUNTED
// vmcnt (T3+T4):
//   q0: A0xB0 (reads A0:8, B0:4)   [stage A1(t+1) -> other slot]
//   q1: A0xB1 (reads B1:4)         [stage A0(t+2) -> current slot]
//   q2: A1xB1 (reads A1:8)         [stage B0(t+2)]
//   q3: A1xB0 (reads 0, B0 live)   [stage B1(t+2)]
// Each stage lands in a region AFTER its last read this step. End-of-step:
// s_waitcnt vmcnt(6) + raw s_barrier -> tile t+1 resident, 6 loads stay in
// flight across the barrier. No __syncthreads in the loop; no ds_writes
// exist, so raw barriers suffice (every ds_read anchored by same-phase MFMA).
// ---------------------------------------------------------------------------
__global__ __launch_bounds__(512, 2)
void score_kernel(const unsigned short* __restrict__ packA,
                  const unsigned short* __restrict__ packB,
                  const float* __restrict__ vnorm,
                  const float* __restrict__ row_x2,
                  const float* __restrict__ row_c,
                  const float* __restrict__ row_sc,
                  const float* __restrict__ head_bias,
                  const float* __restrict__ tail_bias,
                  float* __restrict__ out,
                  int cs, int ns, int nrowA, int nrowB)
{
    extern __shared__ __align__(16) char smem[];   // 2 slots x (A 32KB | B 32KB)

    // XCD-aware remap: each XCD gets 32 contiguous blocks (= 2 whole batches).
    const int orig = blockIdx.x;
    const int wg = (orig & 7) * 32 + (orig >> 3);
    const int bz = wg >> 4;
    const int by = (wg >> 2) & 3;
    const int bx = wg & 3;
    const int m0 = by * 256;
    const int n0 = bx * 256;

    const int tid  = threadIdx.x;
    const int lane = tid & 63;
    const int w    = tid >> 6;
    const int wr   = w >> 2, wn = w & 3;          // 2x4 wave grid, 128x64 each
    const int lrow = lane & 15, lg = lane >> 4;

    f32x4 acc[8][4];
#pragma unroll
    for (int i = 0; i < 8; ++i)
#pragma unroll
        for (int j = 0; j < 4; ++j) acc[i][j] = f32x4{0.f, 0.f, 0.f, 0.f};

    // per-thread constant read bases: row&7 == lrow&7 for all frags
    const int xr = (lg ^ (lrow & 7)) * 16;
    const int baseA = (wr * 128 + lrow) * 128 + xr;           // A frag m: +m*2048
    const int baseB = 32768 + (wn * 64 + lrow) * 128 + xr;    // B frag n: +n*2048
    // lo chunk = hi byte-offset ^ 64

    // stage addressing (linear 8KB chunks: 512 thr x 16B)
    const int s16 = (tid & 255) * 16;
    const int shi = tid >> 8;   // 0 or 1

    const char* gA = (const char*)packA + (size_t)(bz * cs + m0) * 128;
    const char* gB = (const char*)packB + (size_t)(bz * ns + n0) * 128;
    const size_t strA = (size_t)nrowA * 128;   // per-K-tile panel stride
    const size_t strB = (size_t)nrowB * 128;

#define GLL(srcp, dstp)                                                        \
    __builtin_amdgcn_global_load_lds(                                          \
        (const __attribute__((address_space(1))) unsigned int*)(srcp),         \
        (__attribute__((address_space(3))) unsigned int*)(dstp), 16, 0, 0)

    // one 8KB chunk: off0 + (tid&255)*16 + (tid>>8)*sstr  (same offset in LDS)
#define STAGE(dstbase, srcpanel, off0, sstr)                                   \
    do { const int o_ = (off0) + s16 + shi * (sstr);                           \
         GLL((srcpanel) + o_, (dstbase) + o_); } while (0)

    // region chunk maps (block-level rows):
    // A0 = rows {0-63, 128-191}; A1 = {64-127, 192-255}
    // B0 = rows {0-31,64-95,128-159,192-223}; B1 = +32
#define STAGE_A0(d, s) do { STAGE(d, s, 0, 4096);     STAGE(d, s, 16384, 4096); } while (0)
#define STAGE_A1(d, s) do { STAGE(d, s, 8192, 4096);  STAGE(d, s, 24576, 4096); } while (0)
#define STAGE_B0(d, s) do { STAGE(d, s, 0, 8192);     STAGE(d, s, 16384, 8192); } while (0)
#define STAGE_B1(d, s) do { STAGE(d, s, 4096, 8192);  STAGE(d, s, 20480, 8192); } while (0)

#define RD(p, off) (*(const short8v*)((p) + (off)))
#define MFMA_(A_, B_, C_) __builtin_amdgcn_mfma_f32_16x16x32_bf16(A_, B_, C_, 0, 0, 0)

    // one C-quadrant: 4 m-frags (regs ah/al[0..3] -> acc rows MOFF..MOFF+3)
    // x 2 n-frags (bh/bl[NOFF..NOFF+1]) x 3 products = 24 MFMA, dep distance 8
#define QUAD(MOFF, NOFF)                                                       \
    do {                                                                       \
        _Pragma("unroll") for (int mm = 0; mm < 4; ++mm)                       \
        _Pragma("unroll") for (int nn = 0; nn < 2; ++nn)                       \
            acc[(MOFF)+mm][(NOFF)+nn] = MFMA_(ah[mm], bh[(NOFF)+nn], acc[(MOFF)+mm][(NOFF)+nn]); \
        _Pragma("unroll") for (int mm = 0; mm < 4; ++mm)                       \
        _Pragma("unroll") for (int nn = 0; nn < 2; ++nn)                       \
            acc[(MOFF)+mm][(NOFF)+nn] = MFMA_(ah[mm], bl[(NOFF)+nn], acc[(MOFF)+mm][(NOFF)+nn]); \
        _Pragma("unroll") for (int mm = 0; mm < 4; ++mm)                       \
        _Pragma("unroll") for (int nn = 0; nn < 2; ++nn)                       \
            acc[(MOFF)+mm][(NOFF)+nn] = MFMA_(al[mm], bh[(NOFF)+nn], acc[(MOFF)+mm][(NOFF)+nn]); \
    } while (0)

#define BAR()   __builtin_amdgcn_s_barrier()
#define PRIO(x) __builtin_amdgcn_s_setprio(x)

    // ---- prologue: tile0 (8 loads, slot0) + tile1 minus A1 (6 loads, slot1)
    STAGE_A0(smem, gA);               STAGE_A1(smem, gA);
    STAGE_B0(smem + 32768, gB);       STAGE_B1(smem + 32768, gB);
    STAGE_A0(smem + 65536, gA + strA);
    STAGE_B0(smem + 98304, gB + strB);
    STAGE_B1(smem + 98304, gB + strB);
    asm volatile("s_waitcnt vmcnt(6)" ::: "memory");
    BAR();

    short8v ah[4], al[4], bh[4], bl[4];

#pragma unroll 1
    for (int t = 0; t < 16; ++t) {
        char* cur = smem + (t & 1) * 65536;          // slot being read (tile t)
        char* oth = smem + ((t + 1) & 1) * 65536;    // slot of tile t+1
        const char* gA1 = gA + (size_t)(t + 1) * strA;
        const char* gA2 = gA + (size_t)(t + 2) * strA;
        const char* gB2 = gB + (size_t)(t + 2) * strB;

        // ---- q0: stage A1(t+1); read A0 + B0; MFMA A0xB0 ----
        if (t < 15) STAGE_A1(oth, gA1);
#pragma unroll
        for (int m = 0; m < 4; ++m) {
            ah[m] = RD(cur, baseA + m * 2048);
            al[m] = RD(cur, (baseA ^ 64) + m * 2048);
        }
#pragma unroll
        for (int n = 0; n < 2; ++n) {
            bh[n] = RD(cur, baseB + n * 2048);
            bl[n] = RD(cur, (baseB ^ 64) + n * 2048);
        }
        BAR(); PRIO(1); QUAD(0, 0); PRIO(0); BAR();

        // ---- q1: stage A0(t+2) (A0 reads done); read B1; MFMA A0xB1 ----
        if (t < 14) STAGE_A0(cur, gA2);
#pragma unroll
        for (int n = 2; n < 4; ++n) {
            bh[n] = RD(cur, baseB + n * 2048);
            bl[n] = RD(cur, (baseB ^ 64) + n * 2048);
        }
        BAR(); PRIO(1); QUAD(0, 2); PRIO(0); BAR();

        // ---- q2: stage B0(t+2) (B0 reads done); read A1; MFMA A1xB1 ----
        if (t < 14) STAGE_B0(cur + 32768, gB2);
#pragma unroll
        for (int m = 0; m < 4; ++m) {
            ah[m] = RD(cur, baseA + 8192 + m * 2048);
            al[m] = RD(cur, (baseA ^ 64) + 8192 + m * 2048);
        }
        BAR(); PRIO(1); QUAD(4, 2); PRIO(0); BAR();

        // ---- q3: stage B1(t+2) (B1 reads done); MFMA A1xB0 (B0 live) ----
        if (t < 14) STAGE_B1(cur + 32768, gB2);
        BAR(); PRIO(1); QUAD(4, 0); PRIO(0);

        // counted wait: tile t+1 fully resident; tile t+2's 6 loads remain
        if (t <= 13)      asm volatile("s_waitcnt vmcnt(6)" ::: "memory");
        else if (t == 14) asm volatile("s_waitcnt vmcnt(0)" ::: "memory");
        BAR();
    }

    // ---- fused hyperbolic-distance epilogue ----
    // C/D layout (m89-verified): col = lane&15, row = (lane>>4)*4 + q
    const int nbase = n0 + wn * 64 + lrow;
    float rvn[4], vnv[4], tb[4];
#pragma unroll
    for (int j = 0; j < 4; ++j) {
        const int gn = bz * ns + nbase + j * 16;
        const float vn = vnorm[gn];
        vnv[j] = vn;
        rvn[j] = 1.0f / vn;
        tb[j]  = tail_bias[gn];
    }
#pragma unroll
    for (int i = 0; i < 8; ++i) {
#pragma unroll
        for (int q = 0; q < 4; ++q) {
            const int gm = bz * cs + m0 + wr * 128 + i * 16 + lg * 4 + q;
            const float x2  = row_x2[gm];
            const float cc  = row_c[gm];
            const float scq = row_sc[gm];
            const float hb  = head_bias[gm];
            const float rscq = 1.0f / scq;
            float* orow = out + (size_t)gm * ns + nbase;
#pragma unroll
            for (int j = 0; j < 4; ++j) {
                const float xv = acc[i][j][q] * rvn[j];
                float xx = fminf(scq * vnv[j], 15.0f);           // x >= 0 always
                const float ey = __expf(2.0f * xx);
                const float g  = (1.0f - 2.0f / (ey + 1.0f)) * rscq;  // tanh/sqc
                const float c1 = 1.0f - 2.0f*cc*g*xv + cc*g*g;
                const float c2 = 1.0f - cc*x2;
                const float num = sqrtf(fmaxf(c1*c1*x2 + c2*c2*g*g - 2.0f*c1*c2*g*xv, 0.0f));
                const float den = fmaxf(1.0f - 2.0f*cc*g*xv + cc*cc*g*g*x2, MIN_NORM);
                float tt = scq * num * __builtin_amdgcn_rcpf(den);
                tt = fminf(tt, 1.0f - 1e-5f);                    // t >= 0 always
                const float ath = 0.5f * __logf((1.0f + tt) * __builtin_amdgcn_rcpf(1.0f - tt));
                const float dist = 2.0f * rscq * ath;
                orow[j * 16] = -dist * dist + hb + tb[j];
            }
        }
    }
#undef GLL
#undef STAGE
#undef STAGE_A0
#undef STAGE_A1
#undef STAGE_B0
#undef STAGE_B1
#undef RD
#undef MFMA_
#undef QUAD
#undef BAR
#undef PRIO
}

// ---------------------------------------------------------------------------
extern "C" void kernel_launch(void* const* d_in, const int* in_sizes, int n_in,
                              void* d_out, int out_size, void* d_ws, size_t ws_size,
                              hipStream_t stream)
{
    const float* head      = (const float*)d_in[0];
    const float* head_bias = (const float*)d_in[1];
    const float* rel       = (const float*)d_in[2];
    const float* rel_diag  = (const float*)d_in[3];
    const float* curvature = (const float*)d_in[4];
    const float* context   = (const float*)d_in[5];
    const float* scale     = (const float*)d_in[6];
    const float* tail      = (const float*)d_in[7];
    const float* tail_bias = (const float*)d_in[8];

    const int B  = in_sizes[1];        // 16384
    const int T  = in_sizes[8];        // 16384
    const int ns = out_size / B;       // 1024
    const int nc = T / ns;             // 16
    const int cs = B / nc;             // 1024

    // ws layout: packA (16*B*64 us = 32MB) | packB (32MB) | f32 scalars
    unsigned short* packA = (unsigned short*)d_ws;
    unsigned short* packB = packA + (size_t)16 * B * 64;
    float* row_x2 = (float*)(packB + (size_t)16 * T * 64);
    float* row_c  = row_x2 + B;
    float* row_sc = row_c + B;
    float* vnormb = row_sc + B;

    prep_kernel<<<B + T, 64, 0, stream>>>(head, rel, rel_diag, curvature, context,
                                          scale, tail, packA, packB,
                                          row_x2, row_c, row_sc, vnormb, B, T);

    (void)hipFuncSetAttribute((const void*)score_kernel,
                              hipFuncAttributeMaxDynamicSharedMemorySize, 131072);
    const int nblk = (ns / 256) * (cs / 256) * nc;   // 256
    score_kernel<<<nblk, 512, 131072, stream>>>(packA, packB, vnormb, row_x2, row_c,
                                                row_sc, head_bias, tail_bias,
                                                (float*)d_out, cs, ns, B, T);
}

// Round 7
// 130.310 us; speedup vs baseline: 2.5030x; 1.0369x over previous
//
#include <hip/hip_runtime.h>
#include <math.h>

#define DEV static __device__ __forceinline__

constexpr float MIN_NORM = 1e-15f;
constexpr float BALL_EPS = 1e-5f;
constexpr int D = 512;          // feature dim (fixed by problem)

typedef float f32x4 __attribute__((ext_vector_type(4)));
typedef short short8v __attribute__((ext_vector_type(8)));
typedef unsigned short ushort8v __attribute__((ext_vector_type(8)));

DEV float wave_sum(float v) {
#pragma unroll
    for (int o = 32; o > 0; o >>= 1) v += __shfl_xor(v, o, 64);
    return v;
}

DEV float rcpf_(float x) { return __builtin_amdgcn_rcpf(x); }
DEV float rsqf_(float x) { return __builtin_amdgcn_rsqf(x); }

// tanh(a)/a for a >= 0 (returns 0 at a==0; consumer multiplies by ~0 vector)
DEV float tanh_over_a_pos(float a) {
    const float e = __expf(-2.0f * a);
    return (1.0f - e) * rcpf_((1.0f + e) * fmaxf(a, 1e-20f));
}

// bf16 split helpers (RNE)
DEV unsigned short f2bf(float f) {
    unsigned int u = __float_as_uint(f);
    u = (u + 0x7FFFu + ((u >> 16) & 1u)) >> 16;
    return (unsigned short)u;
}
DEV float bf2f(unsigned short h) { return __uint_as_float(((unsigned int)h) << 16); }

// Packed panel layout (exact LDS image; staging is a linear copy):
//   pack[kb][row][slot], kb = K-tile (32 K-elems), slot = 16B chunk 0..7.
//   chunks 0-3 = hi k-sub 0..3, 4-7 = lo. Stored slot = chunk ^ (row & 7).
DEV void write_packed_row(unsigned short* pack, size_t nrow, int row,
                          int lane, ushort8v hi, ushort8v lo)
{
    const int kb  = lane >> 2;
    const int cch = lane & 3;
    const int rx  = row & 7;
    unsigned short* dst = pack + ((size_t)kb * nrow + row) * 64;   // 128B rows
    *(ushort8v*)(dst + ((cch ^ rx) * 8))       = hi;
    *(ushort8v*)(dst + (((cch + 4) ^ rx) * 8)) = lo;
}

// ---------------------------------------------------------------------------
// Merged prep kernel: 256 threads = 4 waves = 4 rows per block.
// Rows [0,B) = head preprocessing; rows [B,B+T) = tail norm+split.
// All transcendental/divide paths use fast HW intrinsics (rcp/rsq/__expf/
// __logf) — absmax headroom is ~17x, fast-math relative error ~1e-6.
// ---------------------------------------------------------------------------
__global__ __launch_bounds__(256)
void prep_kernel(const float* __restrict__ head,
                 const float* __restrict__ rel,
                 const float* __restrict__ rel_diag,
                 const float* __restrict__ curvature,
                 const float* __restrict__ context,
                 const float* __restrict__ scale_p,
                 const float* __restrict__ tail,
                 unsigned short* __restrict__ packA,
                 unsigned short* __restrict__ packB,
                 float* __restrict__ row_x2,
                 float* __restrict__ row_c,
                 float* __restrict__ row_sc,
                 float* __restrict__ vnorm,
                 int B, int T)
{
    const int lane = threadIdx.x & 63;
    const int base = lane * 8;
    const int grow = blockIdx.x * 4 + (threadIdx.x >> 6);   // global row id

    if (grow >= B) {
        // ---- tail path ----
        const int row = grow - B;
        const size_t roff = (size_t)row * D + base;
        float v[8];
        *(float4*)&v[0] = *(const float4*)(tail + roff);
        *(float4*)&v[4] = *(const float4*)(tail + roff + 4);
        float s = 0.0f;
        ushort8v hi, lo;
#pragma unroll
        for (int e = 0; e < 8; ++e) {
            s += v[e]*v[e];
            const unsigned short hb_ = f2bf(v[e]);
            hi[e] = hb_;
            lo[e] = f2bf(v[e] - bf2f(hb_));
        }
        s = wave_sum(s);
        write_packed_row(packB, (size_t)T, row, lane, hi, lo);
        if (lane == 0) vnorm[row] = sqrtf(s);
        return;
    }

    // ---- head path ----
    const int row = grow;
    const size_t roff = (size_t)row * D;
    const size_t doff = (size_t)row * 2 * D;

    float hv[8], rv[8], gv[8], fv[8], cxv[8];
    *(float4*)&hv[0]  = *(const float4*)(head + roff + base);
    *(float4*)&hv[4]  = *(const float4*)(head + roff + base + 4);
    *(float4*)&rv[0]  = *(const float4*)(rel + roff + base);
    *(float4*)&rv[4]  = *(const float4*)(rel + roff + base + 4);
    *(float4*)&gv[0]  = *(const float4*)(rel_diag + doff + base);
    *(float4*)&gv[4]  = *(const float4*)(rel_diag + doff + base + 4);
    *(float4*)&fv[0]  = *(const float4*)(rel_diag + doff + D + base);
    *(float4*)&fv[4]  = *(const float4*)(rel_diag + doff + D + base + 4);
    *(float4*)&cxv[0] = *(const float4*)(context + roff + base);
    *(float4*)&cxv[4] = *(const float4*)(context + roff + base + 4);

    float rq[8], rf[8];
#pragma unroll
    for (int p = 0; p < 4; ++p) {
        const float x0 = hv[2*p], x1 = hv[2*p+1];
        float g0 = gv[2*p], g1 = gv[2*p+1];
        const float gi = rsqf_(fmaxf(g0*g0 + g1*g1, 1e-30f));
        g0 *= gi; g1 *= gi;
        rq[2*p]   = g0*x0 - g1*x1;       // rotation
        rq[2*p+1] = g0*x1 + g1*x0;
        float f0 = fv[2*p], f1 = fv[2*p+1];
        const float fi = rsqf_(fmaxf(f0*f0 + f1*f1, 1e-30f));
        f0 *= fi; f1 *= fi;
        rf[2*p]   = f0*x0 + f1*x1;       // reflection
        rf[2*p+1] = f1*x0 - f0*x1;
    }

    float s0=0,s1=0,s2=0,s3=0,s4=0,s5=0,s6=0,s7=0;
#pragma unroll
    for (int e = 0; e < 8; ++e) {
        s0 += cxv[e]*rf[e];   s1 += cxv[e]*rq[e];
        s2 += rv[e]*rv[e];    s3 += rf[e]*rv[e];
        s4 += rq[e]*rv[e];    s5 += rf[e]*rf[e];
        s6 += rq[e]*rq[e];    s7 += rf[e]*rq[e];
    }
    s0 = wave_sum(s0); s1 = wave_sum(s1); s2 = wave_sum(s2); s3 = wave_sum(s3);
    s4 = wave_sum(s4); s5 = wave_sum(s5); s6 = wave_sum(s6); s7 = wave_sum(s7);

    // c = softplus(curvature)
    const float cu = curvature[row];
    const float c  = fmaxf(cu, 0.0f) + __logf(1.0f + __expf(-fabsf(cu)));
    const float sqc = sqrtf(c);
    const float sc  = scale_p[0];

    // softmax over the 2 candidates
    const float a0 = s0 * sc, a1 = s1 * sc;
    const float mx = fmaxf(a0, a1);
    const float e0 = __expf(a0 - mx), e1 = __expf(a1 - mx);
    const float w0 = e0 * rcpf_(e0 + e1);
    const float w1 = 1.0f - w0;

    const float att2    = fmaxf(w0*w0*s5 + 2.0f*w0*w1*s7 + w1*w1*s6, 0.0f);
    const float attdrel = w0*s3 + w1*s4;
    const float u_att = fmaxf(sqrtf(att2), MIN_NORM);
    const float u_rel = fmaxf(sqrtf(s2), MIN_NORM);

    // expmap0 scale factors (tanh(a)/a, a >= 0)
    const float kl = tanh_over_a_pos(sqc * u_att);
    const float kr = tanh_over_a_pos(sqc * u_rel);

    const float x2 = kl*kl*att2;
    const float y2 = kr*kr*s2;
    const float xy = kl*kr*attdrel;

    const float Am  = 1.0f + 2.0f*c*xy + c*y2;
    const float Bm  = 1.0f - c*x2;
    const float inv_den = rcpf_(fmaxf(1.0f + 2.0f*c*xy + c*c*x2*y2, MIN_NORM));

    float pre[8];
    float r2p = 0.0f;
#pragma unroll
    for (int e = 0; e < 8; ++e) {
        const float attq = w0*rf[e] + w1*rq[e];
        pre[e] = (Am*kl*attq + Bm*kr*rv[e]) * inv_den;
        r2p += pre[e]*pre[e];
    }
    r2p = wave_sum(r2p);

    // project onto the ball
    const float nrm  = fmaxf(sqrtf(r2p), MIN_NORM);
    const float maxn = (1.0f - BALL_EPS) * rcpf_(sqc);
    const float psc  = (nrm > maxn) ? (maxn * rcpf_(nrm)) : 1.0f;

    ushort8v hi, lo;
#pragma unroll
    for (int e = 0; e < 8; ++e) {
        const float o = pre[e] * psc;
        const unsigned short hb_ = f2bf(o);
        hi[e] = hb_;
        lo[e] = f2bf(o - bf2f(hb_));
    }
    write_packed_row(packA, (size_t)B, row, lane, hi, lo);

    if (lane == 0) {
        row_x2[row] = r2p * psc * psc;
        row_c[row]  = c;
        row_sc[row] = sqc;
    }
}

// ---------------------------------------------------------------------------
// Kernel C (UNCHANGED from round 6): 256x256 tile, 8 waves, BK=32 hi|lo
// packed 128B rows, dbuf 128KB, C-quadrant 4-phase schedule, counted vmcnt.
// ---------------------------------------------------------------------------
__global__ __launch_bounds__(512, 2)
void score_kernel(const unsigned short* __restrict__ packA,
                  const unsigned short* __restrict__ packB,
                  const float* __restrict__ vnorm,
                  const float* __restrict__ row_x2,
                  const float* __restrict__ row_c,
                  const float* __restrict__ row_sc,
                  const float* __restrict__ head_bias,
                  const float* __restrict__ tail_bias,
                  float* __restrict__ out,
                  int cs, int ns, int nrowA, int nrowB)
{
    extern __shared__ __align__(16) char smem[];   // 2 slots x (A 32KB | B 32KB)

    // XCD-aware remap: each XCD gets 32 contiguous blocks (= 2 whole batches).
    const int orig = blockIdx.x;
    const int wg = (orig & 7) * 32 + (orig >> 3);
    const int bz = wg >> 4;
    const int by = (wg >> 2) & 3;
    const int bx = wg & 3;
    const int m0 = by * 256;
    const int n0 = bx * 256;

    const int tid  = threadIdx.x;
    const int lane = tid & 63;
    const int w    = tid >> 6;
    const int wr   = w >> 2, wn = w & 3;          // 2x4 wave grid, 128x64 each
    const int lrow = lane & 15, lg = lane >> 4;

    f32x4 acc[8][4];
#pragma unroll
    for (int i = 0; i < 8; ++i)
#pragma unroll
        for (int j = 0; j < 4; ++j) acc[i][j] = f32x4{0.f, 0.f, 0.f, 0.f};

    // per-thread constant read bases: row&7 == lrow&7 for all frags
    const int xr = (lg ^ (lrow & 7)) * 16;
    const int baseA = (wr * 128 + lrow) * 128 + xr;           // A frag m: +m*2048
    const int baseB = 32768 + (wn * 64 + lrow) * 128 + xr;    // B frag n: +n*2048
    // lo chunk = hi byte-offset ^ 64

    // stage addressing (linear 8KB chunks: 512 thr x 16B)
    const int s16 = (tid & 255) * 16;
    const int shi = tid >> 8;   // 0 or 1

    const char* gA = (const char*)packA + (size_t)(bz * cs + m0) * 128;
    const char* gB = (const char*)packB + (size_t)(bz * ns + n0) * 128;
    const size_t strA = (size_t)nrowA * 128;   // per-K-tile panel stride
    const size_t strB = (size_t)nrowB * 128;

#define GLL(srcp, dstp)                                                        \
    __builtin_amdgcn_global_load_lds(                                          \
        (const __attribute__((address_space(1))) unsigned int*)(srcp),         \
        (__attribute__((address_space(3))) unsigned int*)(dstp), 16, 0, 0)

    // one 8KB chunk: off0 + (tid&255)*16 + (tid>>8)*sstr  (same offset in LDS)
#define STAGE(dstbase, srcpanel, off0, sstr)                                   \
    do { const int o_ = (off0) + s16 + shi * (sstr);                           \
         GLL((srcpanel) + o_, (dstbase) + o_); } while (0)

    // region chunk maps (block-level rows):
    // A0 = rows {0-63, 128-191}; A1 = {64-127, 192-255}
    // B0 = rows {0-31,64-95,128-159,192-223}; B1 = +32
#define STAGE_A0(d, s) do { STAGE(d, s, 0, 4096);     STAGE(d, s, 16384, 4096); } while (0)
#define STAGE_A1(d, s) do { STAGE(d, s, 8192, 4096);  STAGE(d, s, 24576, 4096); } while (0)
#define STAGE_B0(d, s) do { STAGE(d, s, 0, 8192);     STAGE(d, s, 16384, 8192); } while (0)
#define STAGE_B1(d, s) do { STAGE(d, s, 4096, 8192);  STAGE(d, s, 20480, 8192); } while (0)

#define RD(p, off) (*(const short8v*)((p) + (off)))
#define MFMA_(A_, B_, C_) __builtin_amdgcn_mfma_f32_16x16x32_bf16(A_, B_, C_, 0, 0, 0)

    // one C-quadrant: 4 m-frags x 2 n-frags x 3 products = 24 MFMA
#define QUAD(MOFF, NOFF)                                                       \
    do {                                                                       \
        _Pragma("unroll") for (int mm = 0; mm < 4; ++mm)                       \
        _Pragma("unroll") for (int nn = 0; nn < 2; ++nn)                       \
            acc[(MOFF)+mm][(NOFF)+nn] = MFMA_(ah[mm], bh[(NOFF)+nn], acc[(MOFF)+mm][(NOFF)+nn]); \
        _Pragma("unroll") for (int mm = 0; mm < 4; ++mm)                       \
        _Pragma("unroll") for (int nn = 0; nn < 2; ++nn)                       \
            acc[(MOFF)+mm][(NOFF)+nn] = MFMA_(ah[mm], bl[(NOFF)+nn], acc[(MOFF)+mm][(NOFF)+nn]); \
        _Pragma("unroll") for (int mm = 0; mm < 4; ++mm)                       \
        _Pragma("unroll") for (int nn = 0; nn < 2; ++nn)                       \
            acc[(MOFF)+mm][(NOFF)+nn] = MFMA_(al[mm], bh[(NOFF)+nn], acc[(MOFF)+mm][(NOFF)+nn]); \
    } while (0)

#define BAR()   __builtin_amdgcn_s_barrier()
#define PRIO(x) __builtin_amdgcn_s_setprio(x)

    // ---- prologue: tile0 (8 loads, slot0) + tile1 minus A1 (6 loads, slot1)
    STAGE_A0(smem, gA);               STAGE_A1(smem, gA);
    STAGE_B0(smem + 32768, gB);       STAGE_B1(smem + 32768, gB);
    STAGE_A0(smem + 65536, gA + strA);
    STAGE_B0(smem + 98304, gB + strB);
    STAGE_B1(smem + 98304, gB + strB);
    asm volatile("s_waitcnt vmcnt(6)" ::: "memory");
    BAR();

    short8v ah[4], al[4], bh[4], bl[4];

#pragma unroll 1
    for (int t = 0; t < 16; ++t) {
        char* cur = smem + (t & 1) * 65536;          // slot being read (tile t)
        char* oth = smem + ((t + 1) & 1) * 65536;    // slot of tile t+1
        const char* gA1 = gA + (size_t)(t + 1) * strA;
        const char* gA2 = gA + (size_t)(t + 2) * strA;
        const char* gB2 = gB + (size_t)(t + 2) * strB;

        // ---- q0: stage A1(t+1); read A0 + B0; MFMA A0xB0 ----
        if (t < 15) STAGE_A1(oth, gA1);
#pragma unroll
        for (int m = 0; m < 4; ++m) {
            ah[m] = RD(cur, baseA + m * 2048);
            al[m] = RD(cur, (baseA ^ 64) + m * 2048);
        }
#pragma unroll
        for (int n = 0; n < 2; ++n) {
            bh[n] = RD(cur, baseB + n * 2048);
            bl[n] = RD(cur, (baseB ^ 64) + n * 2048);
        }
        BAR(); PRIO(1); QUAD(0, 0); PRIO(0); BAR();

        // ---- q1: stage A0(t+2) (A0 reads done); read B1; MFMA A0xB1 ----
        if (t < 14) STAGE_A0(cur, gA2);
#pragma unroll
        for (int n = 2; n < 4; ++n) {
            bh[n] = RD(cur, baseB + n * 2048);
            bl[n] = RD(cur, (baseB ^ 64) + n * 2048);
        }
        BAR(); PRIO(1); QUAD(0, 2); PRIO(0); BAR();

        // ---- q2: stage B0(t+2) (B0 reads done); read A1; MFMA A1xB1 ----
        if (t < 14) STAGE_B0(cur + 32768, gB2);
#pragma unroll
        for (int m = 0; m < 4; ++m) {
            ah[m] = RD(cur, baseA + 8192 + m * 2048);
            al[m] = RD(cur, (baseA ^ 64) + 8192 + m * 2048);
        }
        BAR(); PRIO(1); QUAD(4, 2); PRIO(0); BAR();

        // ---- q3: stage B1(t+2) (B1 reads done); MFMA A1xB0 (B0 live) ----
        if (t < 14) STAGE_B1(cur + 32768, gB2);
        BAR(); PRIO(1); QUAD(4, 0); PRIO(0);

        // counted wait: tile t+1 fully resident; tile t+2's 6 loads remain
        if (t <= 13)      asm volatile("s_waitcnt vmcnt(6)" ::: "memory");
        else if (t == 14) asm volatile("s_waitcnt vmcnt(0)" ::: "memory");
        BAR();
    }

    // ---- fused hyperbolic-distance epilogue ----
    // C/D layout (m89-verified): col = lane&15, row = (lane>>4)*4 + q
    const int nbase = n0 + wn * 64 + lrow;
    float rvn[4], vnv[4], tb[4];
#pragma unroll
    for (int j = 0; j < 4; ++j) {
        const int gn = bz * ns + nbase + j * 16;
        const float vn = vnorm[gn];
        vnv[j] = vn;
        rvn[j] = 1.0f / vn;
        tb[j]  = tail_bias[gn];
    }
#pragma unroll
    for (int i = 0; i < 8; ++i) {
#pragma unroll
        for (int q = 0; q < 4; ++q) {
            const int gm = bz * cs + m0 + wr * 128 + i * 16 + lg * 4 + q;
            const float x2  = row_x2[gm];
            const float cc  = row_c[gm];
            const float scq = row_sc[gm];
            const float hb  = head_bias[gm];
            const float rscq = 1.0f / scq;
            float* orow = out + (size_t)gm * ns + nbase;
#pragma unroll
            for (int j = 0; j < 4; ++j) {
                const float xv = acc[i][j][q] * rvn[j];
                float xx = fminf(scq * vnv[j], 15.0f);           // x >= 0 always
                const float ey = __expf(2.0f * xx);
                const float g  = (1.0f - 2.0f / (ey + 1.0f)) * rscq;  // tanh/sqc
                const float c1 = 1.0f - 2.0f*cc*g*xv + cc*g*g;
                const float c2 = 1.0f - cc*x2;
                const float num = sqrtf(fmaxf(c1*c1*x2 + c2*c2*g*g - 2.0f*c1*c2*g*xv, 0.0f));
                const float den = fmaxf(1.0f - 2.0f*cc*g*xv + cc*cc*g*g*x2, MIN_NORM);
                float tt = scq * num * __builtin_amdgcn_rcpf(den);
                tt = fminf(tt, 1.0f - 1e-5f);                    // t >= 0 always
                const float ath = 0.5f * __logf((1.0f + tt) * __builtin_amdgcn_rcpf(1.0f - tt));
                const float dist = 2.0f * rscq * ath;
                orow[j * 16] = -dist * dist + hb + tb[j];
            }
        }
    }
#undef GLL
#undef STAGE
#undef STAGE_A0
#undef STAGE_A1
#undef STAGE_B0
#undef STAGE_B1
#undef RD
#undef MFMA_
#undef QUAD
#undef BAR
#undef PRIO
}

// ---------------------------------------------------------------------------
extern "C" void kernel_launch(void* const* d_in, const int* in_sizes, int n_in,
                              void* d_out, int out_size, void* d_ws, size_t ws_size,
                              hipStream_t stream)
{
    const float* head      = (const float*)d_in[0];
    const float* head_bias = (const float*)d_in[1];
    const float* rel       = (const float*)d_in[2];
    const float* rel_diag  = (const float*)d_in[3];
    const float* curvature = (const float*)d_in[4];
    const float* context   = (const float*)d_in[5];
    const float* scale     = (const float*)d_in[6];
    const float* tail      = (const float*)d_in[7];
    const float* tail_bias = (const float*)d_in[8];

    const int B  = in_sizes[1];        // 16384
    const int T  = in_sizes[8];        // 16384
    const int ns = out_size / B;       // 1024
    const int nc = T / ns;             // 16
    const int cs = B / nc;             // 1024

    // ws layout: packA (16*B*64 us = 32MB) | packB (32MB) | f32 scalars
    unsigned short* packA = (unsigned short*)d_ws;
    unsigned short* packB = packA + (size_t)16 * B * 64;
    float* row_x2 = (float*)(packB + (size_t)16 * T * 64);
    float* row_c  = row_x2 + B;
    float* row_sc = row_c + B;
    float* vnormb = row_sc + B;

    prep_kernel<<<(B + T) / 4, 256, 0, stream>>>(head, rel, rel_diag, curvature,
                                                 context, scale, tail, packA, packB,
                                                 row_x2, row_c, row_sc, vnormb, B, T);

    (void)hipFuncSetAttribute((const void*)score_kernel,
                              hipFuncAttributeMaxDynamicSharedMemorySize, 131072);
    const int nblk = (ns / 256) * (cs / 256) * nc;   // 256
    score_kernel<<<nblk, 512, 131072, stream>>>(packA, packB, vnormb, row_x2, row_c,
                                                row_sc, head_bias, tail_bias,
                                                (float*)d_out, cs, ns, B, T);
}

// Round 8
// 130.295 us; speedup vs baseline: 2.5033x; 1.0001x over previous
//
#include <hip/hip_runtime.h>
#include <math.h>

#define DEV static __device__ __forceinline__

constexpr float MIN_NORM = 1e-15f;
constexpr float BALL_EPS = 1e-5f;
constexpr int D = 512;          // feature dim (fixed by problem)

typedef float f32x4 __attribute__((ext_vector_type(4)));
typedef short short8v __attribute__((ext_vector_type(8)));
typedef unsigned short ushort8v __attribute__((ext_vector_type(8)));

DEV float wave_sum(float v) {
#pragma unroll
    for (int o = 32; o > 0; o >>= 1) v += __shfl_xor(v, o, 64);
    return v;
}

DEV float rcpf_(float x) { return __builtin_amdgcn_rcpf(x); }
DEV float rsqf_(float x) { return __builtin_amdgcn_rsqf(x); }

// tanh(a)/a for a >= 0
DEV float tanh_over_a_pos(float a) {
    const float e = __expf(-2.0f * a);
    return (1.0f - e) * rcpf_((1.0f + e) * fmaxf(a, 1e-20f));
}

// bf16 split helpers (RNE)
DEV unsigned short f2bf(float f) {
    unsigned int u = __float_as_uint(f);
    u = (u + 0x7FFFu + ((u >> 16) & 1u)) >> 16;
    return (unsigned short)u;
}
DEV float bf2f(unsigned short h) { return __uint_as_float(((unsigned int)h) << 16); }

// Packed panel layout (exact LDS image; staging is a linear copy):
//   pack[kb][row][slot], kb = K-tile (32 K-elems), slot = 16B chunk 0..7.
//   chunks 0-3 = hi k-sub 0..3, 4-7 = lo. Stored slot = chunk ^ (row & 7).
DEV void write_packed_row(unsigned short* pack, size_t nrow, int row,
                          int lane, ushort8v hi, ushort8v lo)
{
    const int kb  = lane >> 2;
    const int cch = lane & 3;
    const int rx  = row & 7;
    unsigned short* dst = pack + ((size_t)kb * nrow + row) * 64;   // 128B rows
    *(ushort8v*)(dst + ((cch ^ rx) * 8))       = hi;
    *(ushort8v*)(dst + (((cch + 4) ^ rx) * 8)) = lo;
}

// ---------------------------------------------------------------------------
// Merged prep kernel (unchanged from round 7): 256 threads = 4 waves = 4 rows.
// ---------------------------------------------------------------------------
__global__ __launch_bounds__(256)
void prep_kernel(const float* __restrict__ head,
                 const float* __restrict__ rel,
                 const float* __restrict__ rel_diag,
                 const float* __restrict__ curvature,
                 const float* __restrict__ context,
                 const float* __restrict__ scale_p,
                 const float* __restrict__ tail,
                 unsigned short* __restrict__ packA,
                 unsigned short* __restrict__ packB,
                 float* __restrict__ row_x2,
                 float* __restrict__ row_c,
                 float* __restrict__ row_sc,
                 float* __restrict__ vnorm,
                 int B, int T)
{
    const int lane = threadIdx.x & 63;
    const int base = lane * 8;
    const int grow = blockIdx.x * 4 + (threadIdx.x >> 6);   // global row id

    if (grow >= B) {
        // ---- tail path ----
        const int row = grow - B;
        const size_t roff = (size_t)row * D + base;
        float v[8];
        *(float4*)&v[0] = *(const float4*)(tail + roff);
        *(float4*)&v[4] = *(const float4*)(tail + roff + 4);
        float s = 0.0f;
        ushort8v hi, lo;
#pragma unroll
        for (int e = 0; e < 8; ++e) {
            s += v[e]*v[e];
            const unsigned short hb_ = f2bf(v[e]);
            hi[e] = hb_;
            lo[e] = f2bf(v[e] - bf2f(hb_));
        }
        s = wave_sum(s);
        write_packed_row(packB, (size_t)T, row, lane, hi, lo);
        if (lane == 0) vnorm[row] = sqrtf(s);
        return;
    }

    // ---- head path ----
    const int row = grow;
    const size_t roff = (size_t)row * D;
    const size_t doff = (size_t)row * 2 * D;

    float hv[8], rv[8], gv[8], fv[8], cxv[8];
    *(float4*)&hv[0]  = *(const float4*)(head + roff + base);
    *(float4*)&hv[4]  = *(const float4*)(head + roff + base + 4);
    *(float4*)&rv[0]  = *(const float4*)(rel + roff + base);
    *(float4*)&rv[4]  = *(const float4*)(rel + roff + base + 4);
    *(float4*)&gv[0]  = *(const float4*)(rel_diag + doff + base);
    *(float4*)&gv[4]  = *(const float4*)(rel_diag + doff + base + 4);
    *(float4*)&fv[0]  = *(const float4*)(rel_diag + doff + D + base);
    *(float4*)&fv[4]  = *(const float4*)(rel_diag + doff + D + base + 4);
    *(float4*)&cxv[0] = *(const float4*)(context + roff + base);
    *(float4*)&cxv[4] = *(const float4*)(context + roff + base + 4);

    float rq[8], rf[8];
#pragma unroll
    for (int p = 0; p < 4; ++p) {
        const float x0 = hv[2*p], x1 = hv[2*p+1];
        float g0 = gv[2*p], g1 = gv[2*p+1];
        const float gi = rsqf_(fmaxf(g0*g0 + g1*g1, 1e-30f));
        g0 *= gi; g1 *= gi;
        rq[2*p]   = g0*x0 - g1*x1;       // rotation
        rq[2*p+1] = g0*x1 + g1*x0;
        float f0 = fv[2*p], f1 = fv[2*p+1];
        const float fi = rsqf_(fmaxf(f0*f0 + f1*f1, 1e-30f));
        f0 *= fi; f1 *= fi;
        rf[2*p]   = f0*x0 + f1*x1;       // reflection
        rf[2*p+1] = f1*x0 - f0*x1;
    }

    float s0=0,s1=0,s2=0,s3=0,s4=0,s5=0,s6=0,s7=0;
#pragma unroll
    for (int e = 0; e < 8; ++e) {
        s0 += cxv[e]*rf[e];   s1 += cxv[e]*rq[e];
        s2 += rv[e]*rv[e];    s3 += rf[e]*rv[e];
        s4 += rq[e]*rv[e];    s5 += rf[e]*rf[e];
        s6 += rq[e]*rq[e];    s7 += rf[e]*rq[e];
    }
    s0 = wave_sum(s0); s1 = wave_sum(s1); s2 = wave_sum(s2); s3 = wave_sum(s3);
    s4 = wave_sum(s4); s5 = wave_sum(s5); s6 = wave_sum(s6); s7 = wave_sum(s7);

    // c = softplus(curvature)
    const float cu = curvature[row];
    const float c  = fmaxf(cu, 0.0f) + __logf(1.0f + __expf(-fabsf(cu)));
    const float sqc = sqrtf(c);
    const float sc  = scale_p[0];

    // softmax over the 2 candidates
    const float a0 = s0 * sc, a1 = s1 * sc;
    const float mx = fmaxf(a0, a1);
    const float e0 = __expf(a0 - mx), e1 = __expf(a1 - mx);
    const float w0 = e0 * rcpf_(e0 + e1);
    const float w1 = 1.0f - w0;

    const float att2    = fmaxf(w0*w0*s5 + 2.0f*w0*w1*s7 + w1*w1*s6, 0.0f);
    const float attdrel = w0*s3 + w1*s4;
    const float u_att = fmaxf(sqrtf(att2), MIN_NORM);
    const float u_rel = fmaxf(sqrtf(s2), MIN_NORM);

    // expmap0 scale factors (tanh(a)/a, a >= 0)
    const float kl = tanh_over_a_pos(sqc * u_att);
    const float kr = tanh_over_a_pos(sqc * u_rel);

    const float x2 = kl*kl*att2;
    const float y2 = kr*kr*s2;
    const float xy = kl*kr*attdrel;

    const float Am  = 1.0f + 2.0f*c*xy + c*y2;
    const float Bm  = 1.0f - c*x2;
    const float inv_den = rcpf_(fmaxf(1.0f + 2.0f*c*xy + c*c*x2*y2, MIN_NORM));

    float pre[8];
    float r2p = 0.0f;
#pragma unroll
    for (int e = 0; e < 8; ++e) {
        const float attq = w0*rf[e] + w1*rq[e];
        pre[e] = (Am*kl*attq + Bm*kr*rv[e]) * inv_den;
        r2p += pre[e]*pre[e];
    }
    r2p = wave_sum(r2p);

    // project onto the ball
    const float nrm  = fmaxf(sqrtf(r2p), MIN_NORM);
    const float maxn = (1.0f - BALL_EPS) * rcpf_(sqc);
    const float psc  = (nrm > maxn) ? (maxn * rcpf_(nrm)) : 1.0f;

    ushort8v hi, lo;
#pragma unroll
    for (int e = 0; e < 8; ++e) {
        const float o = pre[e] * psc;
        const unsigned short hb_ = f2bf(o);
        hi[e] = hb_;
        lo[e] = f2bf(o - bf2f(hb_));
    }
    write_packed_row(packA, (size_t)B, row, lane, hi, lo);

    if (lane == 0) {
        row_x2[row] = r2p * psc * psc;
        row_c[row]  = c;
        row_sc[row] = sqc;
    }
}

// ---------------------------------------------------------------------------
// Kernel C: 256x256 tile, 8 waves, BK=32 hi|lo packed, dbuf 128KB, quadrant
// 4-phase schedule with counted vmcnt — NOW with the m201 phase anchors:
//   BAR ; s_waitcnt lgkmcnt(0) ; sched_barrier(0) ;
//   setprio(1) ; 24 MFMA (pure cluster) ; setprio(0) ; sched_barrier(0) ; BAR
// The sched_barrier(0) fences stop hipcc from dissolving the phase structure
// (raw s_barrier is not a code-motion fence — R5 vs R6 measured identical,
// i.e. the compiler erased the source-level phasing without these anchors).
// ---------------------------------------------------------------------------
__global__ __launch_bounds__(512, 2)
void score_kernel(const unsigned short* __restrict__ packA,
                  const unsigned short* __restrict__ packB,
                  const float* __restrict__ vnorm,
                  const float* __restrict__ row_x2,
                  const float* __restrict__ row_c,
                  const float* __restrict__ row_sc,
                  const float* __restrict__ head_bias,
                  const float* __restrict__ tail_bias,
                  float* __restrict__ out,
                  int cs, int ns, int nrowA, int nrowB)
{
    extern __shared__ __align__(16) char smem[];   // 2 slots x (A 32KB | B 32KB)

    // XCD-aware remap: each XCD gets 32 contiguous blocks (= 2 whole batches).
    const int orig = blockIdx.x;
    const int wg = (orig & 7) * 32 + (orig >> 3);
    const int bz = wg >> 4;
    const int by = (wg >> 2) & 3;
    const int bx = wg & 3;
    const int m0 = by * 256;
    const int n0 = bx * 256;

    const int tid  = threadIdx.x;
    const int lane = tid & 63;
    const int w    = tid >> 6;
    const int wr   = w >> 2, wn = w & 3;          // 2x4 wave grid, 128x64 each
    const int lrow = lane & 15, lg = lane >> 4;

    f32x4 acc[8][4];
#pragma unroll
    for (int i = 0; i < 8; ++i)
#pragma unroll
        for (int j = 0; j < 4; ++j) acc[i][j] = f32x4{0.f, 0.f, 0.f, 0.f};

    // per-thread constant read bases: row&7 == lrow&7 for all frags
    const int xr = (lg ^ (lrow & 7)) * 16;
    const int baseA = (wr * 128 + lrow) * 128 + xr;           // A frag m: +m*2048
    const int baseB = 32768 + (wn * 64 + lrow) * 128 + xr;    // B frag n: +n*2048
    // lo chunk = hi byte-offset ^ 64

    // stage addressing (linear 8KB chunks: 512 thr x 16B)
    const int s16 = (tid & 255) * 16;
    const int shi = tid >> 8;   // 0 or 1

    const char* gA = (const char*)packA + (size_t)(bz * cs + m0) * 128;
    const char* gB = (const char*)packB + (size_t)(bz * ns + n0) * 128;
    const size_t strA = (size_t)nrowA * 128;   // per-K-tile panel stride
    const size_t strB = (size_t)nrowB * 128;

#define GLL(srcp, dstp)                                                        \
    __builtin_amdgcn_global_load_lds(                                          \
        (const __attribute__((address_space(1))) unsigned int*)(srcp),         \
        (__attribute__((address_space(3))) unsigned int*)(dstp), 16, 0, 0)

    // one 8KB chunk: off0 + (tid&255)*16 + (tid>>8)*sstr  (same offset in LDS)
#define STAGE(dstbase, srcpanel, off0, sstr)                                   \
    do { const int o_ = (off0) + s16 + shi * (sstr);                           \
         GLL((srcpanel) + o_, (dstbase) + o_); } while (0)

    // region chunk maps (block-level rows):
    // A0 = rows {0-63, 128-191}; A1 = {64-127, 192-255}
    // B0 = rows {0-31,64-95,128-159,192-223}; B1 = +32
#define STAGE_A0(d, s) do { STAGE(d, s, 0, 4096);     STAGE(d, s, 16384, 4096); } while (0)
#define STAGE_A1(d, s) do { STAGE(d, s, 8192, 4096);  STAGE(d, s, 24576, 4096); } while (0)
#define STAGE_B0(d, s) do { STAGE(d, s, 0, 8192);     STAGE(d, s, 16384, 8192); } while (0)
#define STAGE_B1(d, s) do { STAGE(d, s, 4096, 8192);  STAGE(d, s, 20480, 8192); } while (0)

#define RD(p, off) (*(const short8v*)((p) + (off)))
#define MFMA_(A_, B_, C_) __builtin_amdgcn_mfma_f32_16x16x32_bf16(A_, B_, C_, 0, 0, 0)

    // one C-quadrant: 4 m-frags x 2 n-frags x 3 products = 24 MFMA
#define QUAD(MOFF, NOFF)                                                       \
    do {                                                                       \
        _Pragma("unroll") for (int mm = 0; mm < 4; ++mm)                       \
        _Pragma("unroll") for (int nn = 0; nn < 2; ++nn)                       \
            acc[(MOFF)+mm][(NOFF)+nn] = MFMA_(ah[mm], bh[(NOFF)+nn], acc[(MOFF)+mm][(NOFF)+nn]); \
        _Pragma("unroll") for (int mm = 0; mm < 4; ++mm)                       \
        _Pragma("unroll") for (int nn = 0; nn < 2; ++nn)                       \
            acc[(MOFF)+mm][(NOFF)+nn] = MFMA_(ah[mm], bl[(NOFF)+nn], acc[(MOFF)+mm][(NOFF)+nn]); \
        _Pragma("unroll") for (int mm = 0; mm < 4; ++mm)                       \
        _Pragma("unroll") for (int nn = 0; nn < 2; ++nn)                       \
            acc[(MOFF)+mm][(NOFF)+nn] = MFMA_(al[mm], bh[(NOFF)+nn], acc[(MOFF)+mm][(NOFF)+nn]); \
    } while (0)

#define BAR()   __builtin_amdgcn_s_barrier()
#define PRIO(x) __builtin_amdgcn_s_setprio(x)
#define SBAR()  __builtin_amdgcn_sched_barrier(0)
#define LGKM0() asm volatile("s_waitcnt lgkmcnt(0)" ::: "memory")

    // m201 phase core: anchors pin {mem-issue region | pure MFMA cluster}
#define PHASE_MFMA(MOFF, NOFF)                                                 \
    do {                                                                       \
        BAR();                                                                 \
        LGKM0();                                                               \
        SBAR();                                                                \
        PRIO(1); QUAD(MOFF, NOFF); PRIO(0);                                    \
        SBAR();                                                                \
        BAR();                                                                 \
    } while (0)

    // ---- prologue: tile0 (8 loads, slot0) + tile1 minus A1 (6 loads, slot1)
    STAGE_A0(smem, gA);               STAGE_A1(smem, gA);
    STAGE_B0(smem + 32768, gB);       STAGE_B1(smem + 32768, gB);
    STAGE_A0(smem + 65536, gA + strA);
    STAGE_B0(smem + 98304, gB + strB);
    STAGE_B1(smem + 98304, gB + strB);
    asm volatile("s_waitcnt vmcnt(6)" ::: "memory");
    BAR();

    short8v ah[4], al[4], bh[4], bl[4];

#pragma unroll 1
    for (int t = 0; t < 16; ++t) {
        char* cur = smem + (t & 1) * 65536;          // slot being read (tile t)
        char* oth = smem + ((t + 1) & 1) * 65536;    // slot of tile t+1
        const char* gA1 = gA + (size_t)(t + 1) * strA;
        const char* gA2 = gA + (size_t)(t + 2) * strA;
        const char* gB2 = gB + (size_t)(t + 2) * strB;

        // ---- q0: stage A1(t+1); read A0 + B0; MFMA A0xB0 ----
        if (t < 15) STAGE_A1(oth, gA1);
#pragma unroll
        for (int m = 0; m < 4; ++m) {
            ah[m] = RD(cur, baseA + m * 2048);
            al[m] = RD(cur, (baseA ^ 64) + m * 2048);
        }
#pragma unroll
        for (int n = 0; n < 2; ++n) {
            bh[n] = RD(cur, baseB + n * 2048);
            bl[n] = RD(cur, (baseB ^ 64) + n * 2048);
        }
        PHASE_MFMA(0, 0);

        // ---- q1: stage A0(t+2) (A0 reads done); read B1; MFMA A0xB1 ----
        if (t < 14) STAGE_A0(cur, gA2);
#pragma unroll
        for (int n = 2; n < 4; ++n) {
            bh[n] = RD(cur, baseB + n * 2048);
            bl[n] = RD(cur, (baseB ^ 64) + n * 2048);
        }
        PHASE_MFMA(0, 2);

        // ---- q2: stage B0(t+2) (B0 reads done); read A1; MFMA A1xB1 ----
        if (t < 14) STAGE_B0(cur + 32768, gB2);
#pragma unroll
        for (int m = 0; m < 4; ++m) {
            ah[m] = RD(cur, baseA + 8192 + m * 2048);
            al[m] = RD(cur, (baseA ^ 64) + 8192 + m * 2048);
        }
        PHASE_MFMA(4, 2);

        // ---- q3: stage B1(t+2) (B1 reads done); MFMA A1xB0 (B0 live) ----
        if (t < 14) STAGE_B1(cur + 32768, gB2);
        BAR();
        SBAR();
        PRIO(1); QUAD(4, 0); PRIO(0);
        SBAR();

        // counted wait: tile t+1 fully resident; tile t+2's 6 loads remain
        if (t <= 13)      asm volatile("s_waitcnt vmcnt(6)" ::: "memory");
        else if (t == 14) asm volatile("s_waitcnt vmcnt(0)" ::: "memory");
        BAR();
    }

    // ---- fused hyperbolic-distance epilogue ----
    // C/D layout (m89-verified): col = lane&15, row = (lane>>4)*4 + q
    const int nbase = n0 + wn * 64 + lrow;
    float rvn[4], vnv[4], tb[4];
#pragma unroll
    for (int j = 0; j < 4; ++j) {
        const int gn = bz * ns + nbase + j * 16;
        const float vn = vnorm[gn];
        vnv[j] = vn;
        rvn[j] = 1.0f / vn;
        tb[j]  = tail_bias[gn];
    }
#pragma unroll
    for (int i = 0; i < 8; ++i) {
#pragma unroll
        for (int q = 0; q < 4; ++q) {
            const int gm = bz * cs + m0 + wr * 128 + i * 16 + lg * 4 + q;
            const float x2  = row_x2[gm];
            const float cc  = row_c[gm];
            const float scq = row_sc[gm];
            const float hb  = head_bias[gm];
            const float rscq = 1.0f / scq;
            float* orow = out + (size_t)gm * ns + nbase;
#pragma unroll
            for (int j = 0; j < 4; ++j) {
                const float xv = acc[i][j][q] * rvn[j];
                float xx = fminf(scq * vnv[j], 15.0f);           // x >= 0 always
                const float ey = __expf(2.0f * xx);
                const float g  = (1.0f - 2.0f / (ey + 1.0f)) * rscq;  // tanh/sqc
                const float c1 = 1.0f - 2.0f*cc*g*xv + cc*g*g;
                const float c2 = 1.0f - cc*x2;
                const float num = sqrtf(fmaxf(c1*c1*x2 + c2*c2*g*g - 2.0f*c1*c2*g*xv, 0.0f));
                const float den = fmaxf(1.0f - 2.0f*cc*g*xv + cc*cc*g*g*x2, MIN_NORM);
                float tt = scq * num * __builtin_amdgcn_rcpf(den);
                tt = fminf(tt, 1.0f - 1e-5f);                    // t >= 0 always
                const float ath = 0.5f * __logf((1.0f + tt) * __builtin_amdgcn_rcpf(1.0f - tt));
                const float dist = 2.0f * rscq * ath;
                orow[j * 16] = -dist * dist + hb + tb[j];
            }
        }
    }
#undef GLL
#undef STAGE
#undef STAGE_A0
#undef STAGE_A1
#undef STAGE_B0
#undef STAGE_B1
#undef RD
#undef MFMA_
#undef QUAD
#undef BAR
#undef PRIO
#undef SBAR
#undef LGKM0
#undef PHASE_MFMA
}

// ---------------------------------------------------------------------------
extern "C" void kernel_launch(void* const* d_in, const int* in_sizes, int n_in,
                              void* d_out, int out_size, void* d_ws, size_t ws_size,
                              hipStream_t stream)
{
    const float* head      = (const float*)d_in[0];
    const float* head_bias = (const float*)d_in[1];
    const float* rel       = (const float*)d_in[2];
    const float* rel_diag  = (const float*)d_in[3];
    const float* curvature = (const float*)d_in[4];
    const float* context   = (const float*)d_in[5];
    const float* scale     = (const float*)d_in[6];
    const float* tail      = (const float*)d_in[7];
    const float* tail_bias = (const float*)d_in[8];

    const int B  = in_sizes[1];        // 16384
    const int T  = in_sizes[8];        // 16384
    const int ns = out_size / B;       // 1024
    const int nc = T / ns;             // 16
    const int cs = B / nc;             // 1024

    // ws layout: packA (16*B*64 us = 32MB) | packB (32MB) | f32 scalars
    unsigned short* packA = (unsigned short*)d_ws;
    unsigned short* packB = packA + (size_t)16 * B * 64;
    float* row_x2 = (float*)(packB + (size_t)16 * T * 64);
    float* row_c  = row_x2 + B;
    float* row_sc = row_c + B;
    float* vnormb = row_sc + B;

    prep_kernel<<<(B + T) / 4, 256, 0, stream>>>(head, rel, rel_diag, curvature,
                                                 context, scale, tail, packA, packB,
                                                 row_x2, row_c, row_sc, vnormb, B, T);

    (void)hipFuncSetAttribute((const void*)score_kernel,
                              hipFuncAttributeMaxDynamicSharedMemorySize, 131072);
    const int nblk = (ns / 256) * (cs / 256) * nc;   // 256
    score_kernel<<<nblk, 512, 131072, stream>>>(packA, packB, vnormb, row_x2, row_c,
                                                row_sc, head_bias, tail_bias,
                                                (float*)d_out, cs, ns, B, T);
}

// Round 9
// 126.581 us; speedup vs baseline: 2.5767x; 1.0293x over previous
//
#include <hip/hip_runtime.h>
#include <math.h>

#define DEV static __device__ __forceinline__

constexpr float MIN_NORM = 1e-15f;
constexpr float BALL_EPS = 1e-5f;
constexpr int D = 512;          // feature dim (fixed by problem)

typedef float f32x4 __attribute__((ext_vector_type(4)));
typedef short short8v __attribute__((ext_vector_type(8)));
typedef unsigned short ushort8v __attribute__((ext_vector_type(8)));

DEV float rcpf_(float x) { return __builtin_amdgcn_rcpf(x); }
DEV float rsqf_(float x) { return __builtin_amdgcn_rsqf(x); }

// tanh(a)/a for a >= 0
DEV float tanh_over_a_pos(float a) {
    const float e = __expf(-2.0f * a);
    return (1.0f - e) * rcpf_((1.0f + e) * fmaxf(a, 1e-20f));
}

// bf16 split helpers (RNE)
DEV unsigned short f2bf(float f) {
    unsigned int u = __float_as_uint(f);
    u = (u + 0x7FFFu + ((u >> 16) & 1u)) >> 16;
    return (unsigned short)u;
}
DEV float bf2f(unsigned short h) { return __uint_as_float(((unsigned int)h) << 16); }

// Packed panel layout (exact LDS image; staging is a linear copy):
//   pack[kb][row][slot], kb = K-tile (32 K-elems), slot = 16B chunk 0..7.
//   chunks 0-3 = hi k-sub 0..3, 4-7 = lo. Stored slot = chunk ^ (row & 7).
DEV void write_packed_row(unsigned short* pack, size_t nrow, int row,
                          int lane, ushort8v hi, ushort8v lo)
{
    const int kb  = lane >> 2;
    const int cch = lane & 3;
    const int rx  = row & 7;
    unsigned short* dst = pack + ((size_t)kb * nrow + row) * 64;   // 128B rows
    *(ushort8v*)(dst + ((cch ^ rx) * 8))       = hi;
    *(ushort8v*)(dst + (((cch + 4) ^ rx) * 8)) = lo;
}

// ---------------------------------------------------------------------------
// Merged prep kernel: 2 ROWS PER WAVE (amortize the serial scalar chain,
// double per-wave MLP). 256 threads = 4 waves = 8 rows/block.
// Rows [0,B) = head preprocessing; rows [B,B+T) = tail norm+split.
// B is even, so a wave's row pair never straddles the head/tail boundary.
// ---------------------------------------------------------------------------
__global__ __launch_bounds__(256)
void prep_kernel(const float* __restrict__ head,
                 const float* __restrict__ rel,
                 const float* __restrict__ rel_diag,
                 const float* __restrict__ curvature,
                 const float* __restrict__ context,
                 const float* __restrict__ scale_p,
                 const float* __restrict__ tail,
                 unsigned short* __restrict__ packA,
                 unsigned short* __restrict__ packB,
                 float* __restrict__ row_x2,
                 float* __restrict__ row_c,
                 float* __restrict__ row_sc,
                 float* __restrict__ vnorm,
                 int B, int T)
{
    const int lane = threadIdx.x & 63;
    const int base = lane * 8;
    const int wid  = blockIdx.x * 4 + (threadIdx.x >> 6);
    const int r0   = wid * 2;                       // first of the row pair

    if (r0 >= B) {
        // ---- tail path: 2 rows, loads hoisted ----
        const int tr = r0 - B;
        float v[2][8];
#pragma unroll
        for (int rr = 0; rr < 2; ++rr) {
            const size_t off = (size_t)(tr + rr) * D + base;
            *(float4*)&v[rr][0] = *(const float4*)(tail + off);
            *(float4*)&v[rr][4] = *(const float4*)(tail + off + 4);
        }
        float s[2] = {0.f, 0.f};
        ushort8v hi[2], lo[2];
#pragma unroll
        for (int rr = 0; rr < 2; ++rr)
#pragma unroll
            for (int e = 0; e < 8; ++e) {
                s[rr] += v[rr][e] * v[rr][e];
                const unsigned short hb_ = f2bf(v[rr][e]);
                hi[rr][e] = hb_;
                lo[rr][e] = f2bf(v[rr][e] - bf2f(hb_));
            }
#pragma unroll
        for (int o = 32; o > 0; o >>= 1)
#pragma unroll
            for (int rr = 0; rr < 2; ++rr)
                s[rr] += __shfl_xor(s[rr], o, 64);
#pragma unroll
        for (int rr = 0; rr < 2; ++rr) {
            write_packed_row(packB, (size_t)T, tr + rr, lane, hi[rr], lo[rr]);
            if (lane == 0) vnorm[tr + rr] = sqrtf(s[rr]);
        }
        return;
    }

    // ---- head path: 2 rows, all loads hoisted, reduce chains interleaved ----
    float hv[2][8], rv[2][8], gv[2][8], fv[2][8], cxv[2][8];
#pragma unroll
    for (int rr = 0; rr < 2; ++rr) {
        const size_t roff = (size_t)(r0 + rr) * D + base;
        const size_t doff = (size_t)(r0 + rr) * 2 * D + base;
        *(float4*)&hv[rr][0]  = *(const float4*)(head + roff);
        *(float4*)&hv[rr][4]  = *(const float4*)(head + roff + 4);
        *(float4*)&rv[rr][0]  = *(const float4*)(rel + roff);
        *(float4*)&rv[rr][4]  = *(const float4*)(rel + roff + 4);
        *(float4*)&gv[rr][0]  = *(const float4*)(rel_diag + doff);
        *(float4*)&gv[rr][4]  = *(const float4*)(rel_diag + doff + 4);
        *(float4*)&fv[rr][0]  = *(const float4*)(rel_diag + doff + D);
        *(float4*)&fv[rr][4]  = *(const float4*)(rel_diag + doff + D + 4);
        *(float4*)&cxv[rr][0] = *(const float4*)(context + roff);
        *(float4*)&cxv[rr][4] = *(const float4*)(context + roff + 4);
    }

    float rq[2][8], rf[2][8];
#pragma unroll
    for (int rr = 0; rr < 2; ++rr)
#pragma unroll
        for (int p = 0; p < 4; ++p) {
            const float x0 = hv[rr][2*p], x1 = hv[rr][2*p+1];
            float g0 = gv[rr][2*p], g1 = gv[rr][2*p+1];
            const float gi = rsqf_(fmaxf(g0*g0 + g1*g1, 1e-30f));
            g0 *= gi; g1 *= gi;
            rq[rr][2*p]   = g0*x0 - g1*x1;       // rotation
            rq[rr][2*p+1] = g0*x1 + g1*x0;
            float f0 = fv[rr][2*p], f1 = fv[rr][2*p+1];
            const float fi = rsqf_(fmaxf(f0*f0 + f1*f1, 1e-30f));
            f0 *= fi; f1 *= fi;
            rf[rr][2*p]   = f0*x0 + f1*x1;       // reflection
            rf[rr][2*p+1] = f1*x0 - f0*x1;
        }

    float s[2][8];
#pragma unroll
    for (int rr = 0; rr < 2; ++rr) {
#pragma unroll
        for (int k = 0; k < 8; ++k) s[rr][k] = 0.f;
#pragma unroll
        for (int e = 0; e < 8; ++e) {
            s[rr][0] += cxv[rr][e]*rf[rr][e];   s[rr][1] += cxv[rr][e]*rq[rr][e];
            s[rr][2] += rv[rr][e]*rv[rr][e];    s[rr][3] += rf[rr][e]*rv[rr][e];
            s[rr][4] += rq[rr][e]*rv[rr][e];    s[rr][5] += rf[rr][e]*rf[rr][e];
            s[rr][6] += rq[rr][e]*rq[rr][e];    s[rr][7] += rf[rr][e]*rq[rr][e];
        }
    }
    // 16 interleaved butterfly chains
#pragma unroll
    for (int o = 32; o > 0; o >>= 1)
#pragma unroll
        for (int rr = 0; rr < 2; ++rr)
#pragma unroll
            for (int k = 0; k < 8; ++k)
                s[rr][k] += __shfl_xor(s[rr][k], o, 64);

    const float sc = scale_p[0];
    float pre[2][8], r2p[2];
    float cS[2], sqcS[2];
#pragma unroll
    for (int rr = 0; rr < 2; ++rr) {
        const float cu = curvature[r0 + rr];
        const float c  = fmaxf(cu, 0.0f) + __logf(1.0f + __expf(-fabsf(cu)));
        const float sqc = sqrtf(c);
        cS[rr] = c; sqcS[rr] = sqc;

        const float a0 = s[rr][0] * sc, a1 = s[rr][1] * sc;
        const float mx = fmaxf(a0, a1);
        const float e0 = __expf(a0 - mx), e1 = __expf(a1 - mx);
        const float w0 = e0 * rcpf_(e0 + e1);
        const float w1 = 1.0f - w0;

        const float att2    = fmaxf(w0*w0*s[rr][5] + 2.0f*w0*w1*s[rr][7] + w1*w1*s[rr][6], 0.0f);
        const float attdrel = w0*s[rr][3] + w1*s[rr][4];
        const float u_att = fmaxf(sqrtf(att2), MIN_NORM);
        const float u_rel = fmaxf(sqrtf(s[rr][2]), MIN_NORM);

        const float kl = tanh_over_a_pos(sqc * u_att);
        const float kr = tanh_over_a_pos(sqc * u_rel);

        const float x2 = kl*kl*att2;
        const float y2 = kr*kr*s[rr][2];
        const float xy = kl*kr*attdrel;

        const float Am  = 1.0f + 2.0f*c*xy + c*y2;
        const float Bm  = 1.0f - c*x2;
        const float inv_den = rcpf_(fmaxf(1.0f + 2.0f*c*xy + c*c*x2*y2, MIN_NORM));

        r2p[rr] = 0.f;
#pragma unroll
        for (int e = 0; e < 8; ++e) {
            const float attq = w0*rf[rr][e] + w1*rq[rr][e];
            pre[rr][e] = (Am*kl*attq + Bm*kr*rv[rr][e]) * inv_den;
            r2p[rr] += pre[rr][e]*pre[rr][e];
        }
    }
    // interleaved reduce of the 2 projection norms
#pragma unroll
    for (int o = 32; o > 0; o >>= 1)
#pragma unroll
        for (int rr = 0; rr < 2; ++rr)
            r2p[rr] += __shfl_xor(r2p[rr], o, 64);

#pragma unroll
    for (int rr = 0; rr < 2; ++rr) {
        const float nrm  = fmaxf(sqrtf(r2p[rr]), MIN_NORM);
        const float maxn = (1.0f - BALL_EPS) * rcpf_(sqcS[rr]);
        const float psc  = (nrm > maxn) ? (maxn * rcpf_(nrm)) : 1.0f;

        ushort8v hi, lo;
#pragma unroll
        for (int e = 0; e < 8; ++e) {
            const float o = pre[rr][e] * psc;
            const unsigned short hb_ = f2bf(o);
            hi[e] = hb_;
            lo[e] = f2bf(o - bf2f(hb_));
        }
        write_packed_row(packA, (size_t)B, r0 + rr, lane, hi, lo);

        if (lane == 0) {
            row_x2[r0 + rr] = r2p[rr] * psc * psc;
            row_c[r0 + rr]  = cS[rr];
            row_sc[r0 + rr] = sqcS[rr];
        }
    }
}

// ---------------------------------------------------------------------------
// Kernel C: 256x256 tile, 8 waves, BK=32 hi|lo packed, dbuf 128KB —
// ONE barrier + ONE vmcnt(0) per K-step (was 9 barriers: R5/R6/R8 identical
// at 83-85us because barrier rendezvous drift ~9x500cyc dominated).
// Correctness of the single barrier: each wave's ds_reads of tile t are
// consumed by its own MFMAs before it reaches the step-end barrier, so a
// wave at step t+1 overwriting the OTHER slot cannot race; staging for t+1
// is issued at the top of step t and drained by the step-end vmcnt(0)
// (cover = full step of ds_read+MFMA work >> L2 latency).
// ---------------------------------------------------------------------------
__global__ __launch_bounds__(512, 2)
void score_kernel(const unsigned short* __restrict__ packA,
                  const unsigned short* __restrict__ packB,
                  const float* __restrict__ vnorm,
                  const float* __restrict__ row_x2,
                  const float* __restrict__ row_c,
                  const float* __restrict__ row_sc,
                  const float* __restrict__ head_bias,
                  const float* __restrict__ tail_bias,
                  float* __restrict__ out,
                  int cs, int ns, int nrowA, int nrowB)
{
    extern __shared__ __align__(16) char smem[];   // 2 slots x (A 32KB | B 32KB)

    // XCD-aware remap: each XCD gets 32 contiguous blocks (= 2 whole batches).
    const int orig = blockIdx.x;
    const int wg = (orig & 7) * 32 + (orig >> 3);
    const int bz = wg >> 4;
    const int by = (wg >> 2) & 3;
    const int bx = wg & 3;
    const int m0 = by * 256;
    const int n0 = bx * 256;

    const int tid  = threadIdx.x;
    const int lane = tid & 63;
    const int w    = tid >> 6;
    const int wr   = w >> 2, wn = w & 3;          // 2x4 wave grid, 128x64 each
    const int lrow = lane & 15, lg = lane >> 4;

    f32x4 acc[8][4];
#pragma unroll
    for (int i = 0; i < 8; ++i)
#pragma unroll
        for (int j = 0; j < 4; ++j) acc[i][j] = f32x4{0.f, 0.f, 0.f, 0.f};

    // per-thread constant read bases: row&7 == lrow&7 for all frags
    const int xr = (lg ^ (lrow & 7)) * 16;
    const int baseA = (wr * 128 + lrow) * 128 + xr;           // A frag m: +m*2048
    const int baseB = 32768 + (wn * 64 + lrow) * 128 + xr;    // B frag n: +n*2048
    // lo chunk = hi byte-offset ^ 64

    // stage addressing (linear 8KB chunks: 512 thr x 16B)
    const int s16 = (tid & 255) * 16;
    const int shi = tid >> 8;   // 0 or 1

    const char* gA = (const char*)packA + (size_t)(bz * cs + m0) * 128;
    const char* gB = (const char*)packB + (size_t)(bz * ns + n0) * 128;
    const size_t strA = (size_t)nrowA * 128;   // per-K-tile panel stride
    const size_t strB = (size_t)nrowB * 128;

#define GLL(srcp, dstp)                                                        \
    __builtin_amdgcn_global_load_lds(                                          \
        (const __attribute__((address_space(1))) unsigned int*)(srcp),         \
        (__attribute__((address_space(3))) unsigned int*)(dstp), 16, 0, 0)

    // one 8KB chunk: off0 + (tid&255)*16 + (tid>>8)*sstr  (same offset in LDS)
#define STAGE(dstbase, srcpanel, off0, sstr)                                   \
    do { const int o_ = (off0) + s16 + shi * (sstr);                           \
         GLL((srcpanel) + o_, (dstbase) + o_); } while (0)

    // full-tile stage: A panel (32KB) + B panel (32KB), 8 GLL per thread
#define STAGE_ALL(dstslot, srcA, srcB)                                         \
    do {                                                                       \
        STAGE(dstslot, srcA, 0, 4096);      STAGE(dstslot, srcA, 16384, 4096); \
        STAGE(dstslot, srcA, 8192, 4096);   STAGE(dstslot, srcA, 24576, 4096); \
        STAGE((dstslot)+32768, srcB, 0, 8192);                                 \
        STAGE((dstslot)+32768, srcB, 16384, 8192);                             \
        STAGE((dstslot)+32768, srcB, 4096, 8192);                              \
        STAGE((dstslot)+32768, srcB, 20480, 8192);                             \
    } while (0)

#define RD(p, off) (*(const short8v*)((p) + (off)))
#define MFMA_(A_, B_, C_) __builtin_amdgcn_mfma_f32_16x16x32_bf16(A_, B_, C_, 0, 0, 0)

    // one C-quadrant: 4 m-frags x 2 n-frags x 3 products = 24 MFMA
#define QUAD(MOFF, NOFF)                                                       \
    do {                                                                       \
        _Pragma("unroll") for (int mm = 0; mm < 4; ++mm)                       \
        _Pragma("unroll") for (int nn = 0; nn < 2; ++nn)                       \
            acc[(MOFF)+mm][(NOFF)+nn] = MFMA_(ah[mm], bh[(NOFF)+nn], acc[(MOFF)+mm][(NOFF)+nn]); \
        _Pragma("unroll") for (int mm = 0; mm < 4; ++mm)                       \
        _Pragma("unroll") for (int nn = 0; nn < 2; ++nn)                       \
            acc[(MOFF)+mm][(NOFF)+nn] = MFMA_(ah[mm], bl[(NOFF)+nn], acc[(MOFF)+mm][(NOFF)+nn]); \
        _Pragma("unroll") for (int mm = 0; mm < 4; ++mm)                       \
        _Pragma("unroll") for (int nn = 0; nn < 2; ++nn)                       \
            acc[(MOFF)+mm][(NOFF)+nn] = MFMA_(al[mm], bh[(NOFF)+nn], acc[(MOFF)+mm][(NOFF)+nn]); \
    } while (0)

#define BAR()   __builtin_amdgcn_s_barrier()
#define VM0()   asm volatile("s_waitcnt vmcnt(0)" ::: "memory")

    // ---- prologue: tile0 -> slot0 ----
    STAGE_ALL(smem, gA, gB);
    VM0();
    BAR();

    short8v ah[4], al[4], bh[4], bl[4];

#pragma unroll 1
    for (int t = 0; t < 16; ++t) {
        char* cur = smem + (t & 1) * 65536;          // holds tile t
        char* oth = smem + ((t + 1) & 1) * 65536;

        // stage tile t+1 first (max vmcnt cover under this step's compute)
        if (t < 15)
            STAGE_ALL(oth, gA + (size_t)(t + 1) * strA, gB + (size_t)(t + 1) * strB);

        // ---- full K-step compute: 24 ds_read + 96 MFMA, no barriers ----
        // q0: A0 x B0
#pragma unroll
        for (int m = 0; m < 4; ++m) {
            ah[m] = RD(cur, baseA + m * 2048);
            al[m] = RD(cur, (baseA ^ 64) + m * 2048);
        }
#pragma unroll
        for (int n = 0; n < 2; ++n) {
            bh[n] = RD(cur, baseB + n * 2048);
            bl[n] = RD(cur, (baseB ^ 64) + n * 2048);
        }
        QUAD(0, 0);
        // q1: A0 x B1
#pragma unroll
        for (int n = 2; n < 4; ++n) {
            bh[n] = RD(cur, baseB + n * 2048);
            bl[n] = RD(cur, (baseB ^ 64) + n * 2048);
        }
        QUAD(0, 2);
        // q2: A1 x B1
#pragma unroll
        for (int m = 0; m < 4; ++m) {
            ah[m] = RD(cur, baseA + 8192 + m * 2048);
            al[m] = RD(cur, (baseA ^ 64) + 8192 + m * 2048);
        }
        QUAD(4, 2);
        // q3: A1 x B0 (B0 still live)
        QUAD(4, 0);

        // single end-of-step sync: my 8 staging loads for t+1 have landed
        VM0();
        BAR();
    }

    // ---- fused hyperbolic-distance epilogue ----
    // C/D layout (m89-verified): col = lane&15, row = (lane>>4)*4 + q
    const int nbase = n0 + wn * 64 + lrow;
    float rvn[4], vnv[4], tb[4];
#pragma unroll
    for (int j = 0; j < 4; ++j) {
        const int gn = bz * ns + nbase + j * 16;
        const float vn = vnorm[gn];
        vnv[j] = vn;
        rvn[j] = 1.0f / vn;
        tb[j]  = tail_bias[gn];
    }
#pragma unroll
    for (int i = 0; i < 8; ++i) {
#pragma unroll
        for (int q = 0; q < 4; ++q) {
            const int gm = bz * cs + m0 + wr * 128 + i * 16 + lg * 4 + q;
            const float x2  = row_x2[gm];
            const float cc  = row_c[gm];
            const float scq = row_sc[gm];
            const float hb  = head_bias[gm];
            const float rscq = 1.0f / scq;
            float* orow = out + (size_t)gm * ns + nbase;
#pragma unroll
            for (int j = 0; j < 4; ++j) {
                const float xv = acc[i][j][q] * rvn[j];
                float xx = fminf(scq * vnv[j], 15.0f);           // x >= 0 always
                const float ey = __expf(2.0f * xx);
                const float g  = (1.0f - 2.0f / (ey + 1.0f)) * rscq;  // tanh/sqc
                const float c1 = 1.0f - 2.0f*cc*g*xv + cc*g*g;
                const float c2 = 1.0f - cc*x2;
                const float num = sqrtf(fmaxf(c1*c1*x2 + c2*c2*g*g - 2.0f*c1*c2*g*xv, 0.0f));
                const float den = fmaxf(1.0f - 2.0f*cc*g*xv + cc*cc*g*g*x2, MIN_NORM);
                float tt = scq * num * __builtin_amdgcn_rcpf(den);
                tt = fminf(tt, 1.0f - 1e-5f);                    // t >= 0 always
                const float ath = 0.5f * __logf((1.0f + tt) * __builtin_amdgcn_rcpf(1.0f - tt));
                const float dist = 2.0f * rscq * ath;
                orow[j * 16] = -dist * dist + hb + tb[j];
            }
        }
    }
#undef GLL
#undef STAGE
#undef STAGE_ALL
#undef RD
#undef MFMA_
#undef QUAD
#undef BAR
#undef VM0
}

// ---------------------------------------------------------------------------
extern "C" void kernel_launch(void* const* d_in, const int* in_sizes, int n_in,
                              void* d_out, int out_size, void* d_ws, size_t ws_size,
                              hipStream_t stream)
{
    const float* head      = (const float*)d_in[0];
    const float* head_bias = (const float*)d_in[1];
    const float* rel       = (const float*)d_in[2];
    const float* rel_diag  = (const float*)d_in[3];
    const float* curvature = (const float*)d_in[4];
    const float* context   = (const float*)d_in[5];
    const float* scale     = (const float*)d_in[6];
    const float* tail      = (const float*)d_in[7];
    const float* tail_bias = (const float*)d_in[8];

    const int B  = in_sizes[1];        // 16384
    const int T  = in_sizes[8];        // 16384
    const int ns = out_size / B;       // 1024
    const int nc = T / ns;             // 16
    const int cs = B / nc;             // 1024

    // ws layout: packA (16*B*64 us = 32MB) | packB (32MB) | f32 scalars
    unsigned short* packA = (unsigned short*)d_ws;
    unsigned short* packB = packA + (size_t)16 * B * 64;
    float* row_x2 = (float*)(packB + (size_t)16 * T * 64);
    float* row_c  = row_x2 + B;
    float* row_sc = row_c + B;
    float* vnormb = row_sc + B;

    prep_kernel<<<(B + T) / 8, 256, 0, stream>>>(head, rel, rel_diag, curvature,
                                                 context, scale, tail, packA, packB,
                                                 row_x2, row_c, row_sc, vnormb, B, T);

    (void)hipFuncSetAttribute((const void*)score_kernel,
                              hipFuncAttributeMaxDynamicSharedMemorySize, 131072);
    const int nblk = (ns / 256) * (cs / 256) * nc;   // 256
    score_kernel<<<nblk, 512, 131072, stream>>>(packA, packB, vnormb, row_x2, row_c,
                                                row_sc, head_bias, tail_bias,
                                                (float*)d_out, cs, ns, B, T);
}